// Round 12
// baseline (6941.222 us; speedup 1.0000x reference)
//
#include <hip/hip_runtime.h>
#include <hip/hip_bf16.h>
#include <stdint.h>

#define DD   1024
#define TD   3072
#define DFFN 4096
#define NL   12
#define SS   1040
#define SP   1056          /* padded seq for attention operand arena */
#define BB   8
#define MM   (BB*SS)       /* 8320 */
#define MP   8448          /* M padded to 33*256 for 256-tile GEMM */
#define HH   16
#define NTAIL 16           /* leading tail blocks in attn_staged grid */

typedef float  f32x4  __attribute__((ext_vector_type(4)));
typedef __bf16 bf16x8 __attribute__((ext_vector_type(8)));
typedef unsigned short u16;

union Bf8 { bf16x8 v; u16 s[8]; };

__device__ __forceinline__ u16 f2b(float f) {
  union { float f; unsigned u; } x; x.f = f;
  unsigned r = (x.u + 0x7FFFu + ((x.u >> 16) & 1u)) >> 16;
  return (u16)r;
}

__device__ __forceinline__ f32x4 mfma_bf16(bf16x8 a, bf16x8 b, f32x4 c) {
  return __builtin_amdgcn_mfma_f32_16x16x32_bf16(a, b, c, 0, 0, 0);
}

__device__ __forceinline__ void gload_lds16(const u16* g, u16* l) {
  __builtin_amdgcn_global_load_lds((const __attribute__((address_space(1))) void*)g,
                                   (__attribute__((address_space(3))) void*)l, 16, 0, 0);
}

// 16-lane max reduce via DPP (quad_perm xor1, xor2, row_ror:4, row_ror:8) — VALU-speed.
__device__ __forceinline__ float dppmax16(float t) {
  union { float f; int i; } u, v;
  u.f = t;
  v.i = __builtin_amdgcn_update_dpp(0, u.i, 0xB1, 0xF, 0xF, true);   // quad_perm [1,0,3,2]
  u.f = fmaxf(u.f, v.f);
  v.i = __builtin_amdgcn_update_dpp(0, u.i, 0x4E, 0xF, 0xF, true);   // quad_perm [2,3,0,1]
  u.f = fmaxf(u.f, v.f);
  v.i = __builtin_amdgcn_update_dpp(0, u.i, 0x124, 0xF, 0xF, true);  // row_ror:4
  u.f = fmaxf(u.f, v.f);
  v.i = __builtin_amdgcn_update_dpp(0, u.i, 0x128, 0xF, 0xF, true);  // row_ror:8
  u.f = fmaxf(u.f, v.f);
  return u.f;
}

// ---------------- weight cast+transpose: in (K,N) f32 -> out (N,K) bf16, per layer z ----
__global__ __launch_bounds__(256)
void transpose_cast(const float* __restrict__ in, u16* __restrict__ out, int K, int N) {
  __shared__ float tile[32][33];
  const int n0 = blockIdx.x * 32, k0 = blockIdx.y * 32;
  const size_t lb = (size_t)blockIdx.z * K * N;
  const int tx = threadIdx.x, ty = threadIdx.y;
  for (int j = 0; j < 4; ++j)
    tile[ty + 8*j][tx] = in[lb + (size_t)(k0 + ty + 8*j) * N + n0 + tx];
  __syncthreads();
  for (int j = 0; j < 4; ++j)
    out[lb + (size_t)(n0 + ty + 8*j) * K + k0 + tx] = f2b(tile[tx][ty + 8*j]);
}

// ---------------- LayerNorm: row of 1024, OUTF=0 -> bf16 out, OUTF=1 -> f32 out --------
template<int OUTF>
__global__ __launch_bounds__(256)
void ln_kernel(const float* __restrict__ in, const float* __restrict__ gam,
               const float* __restrict__ bet, u16* __restrict__ outb, float* __restrict__ outf) {
  const int row = blockIdx.x, t = threadIdx.x;
  const float4 v = ((const float4*)(in + (size_t)row * DD))[t];
  float s  = v.x + v.y + v.z + v.w;
  float s2 = v.x*v.x + v.y*v.y + v.z*v.z + v.w*v.w;
  for (int off = 1; off < 64; off <<= 1) { s += __shfl_xor(s, off); s2 += __shfl_xor(s2, off); }
  __shared__ float red[8];
  if ((t & 63) == 0) { red[t >> 6] = s; red[4 + (t >> 6)] = s2; }
  __syncthreads();
  s  = red[0] + red[1] + red[2] + red[3];
  s2 = red[4] + red[5] + red[6] + red[7];
  const float mu = s * (1.0f/1024.0f);
  const float var = s2 * (1.0f/1024.0f) - mu*mu;
  const float rs = rsqrtf(var + 1e-6f);
  const float4 gv = ((const float4*)gam)[t];
  const float4 bv = ((const float4*)bet)[t];
  const float y0 = (v.x - mu)*rs*gv.x + bv.x;
  const float y1 = (v.y - mu)*rs*gv.y + bv.y;
  const float y2 = (v.z - mu)*rs*gv.z + bv.z;
  const float y3 = (v.w - mu)*rs*gv.w + bv.w;
  if (OUTF) {
    float4 o; o.x=y0; o.y=y1; o.z=y2; o.w=y3;
    ((float4*)(outf + (size_t)row * DD))[t] = o;
  } else {
    ushort4 o; o.x=f2b(y0); o.y=f2b(y1); o.z=f2b(y2); o.w=f2b(y3);
    ((ushort4*)(outb + (size_t)row * DD))[t] = o;
  }
}

// ---------------- 128² GEMM (N=1024 shapes): C = A @ Bt^T + bias [+ epi] --------------
// EPI 1: gelu, write bf16.  EPI 2: +resid, write f32.
template<int EPI>
__global__ __launch_bounds__(256, 2)
void gemm_bt(const u16* __restrict__ A, const u16* __restrict__ Bt,
             const float* __restrict__ bias, const float* __restrict__ resid,
             float* outF, u16* outB, int N, int K) {
  __shared__ u16 As[128*64];
  __shared__ u16 Bs[128*64];
  const int tid = threadIdx.x;

  const int nwg = gridDim.x * gridDim.y;
  int wgid = blockIdx.y * gridDim.x + blockIdx.x;
  wgid = (wgid & 7) * (nwg >> 3) + (wgid >> 3);
  const int mb = wgid % gridDim.x;
  const int nb = wgid / gridDim.x;
  const int m0 = mb * 128, n0 = nb * 128;

  const int lane = tid & 63, w = tid >> 6;
  const int wr = (w >> 1) * 64, wc = (w & 1) * 64;
  const int c = lane & 15, g = lane >> 4;

  f32x4 acc[4][4];
  for (int i = 0; i < 4; ++i) for (int j = 0; j < 4; ++j) acc[i][j] = f32x4{0.f,0.f,0.f,0.f};

  const int srow = tid >> 3, scg = tid & 7;
  const size_t aoff = (size_t)(m0 + srow) * K + scg * 8;
  const size_t boff = (size_t)(n0 + srow) * K + scg * 8;

  for (int kt = 0; kt < K; kt += 64) {
    for (int it = 0; it < 4; ++it) {
      gload_lds16(A  + aoff + (size_t)it * 32 * K + kt, As + (it*256 + tid) * 8);
      gload_lds16(Bt + boff + (size_t)it * 32 * K + kt, Bs + (it*256 + tid) * 8);
    }
    __syncthreads();
    for (int kk = 0; kk < 2; ++kk) {
      bf16x8 af[4], bfr[4];
      for (int i = 0; i < 4; ++i) af[i]  = *(const bf16x8*)(As + (wr + i*16 + c)*64 + kk*32 + g*8);
      for (int j = 0; j < 4; ++j) bfr[j] = *(const bf16x8*)(Bs + (wc + j*16 + c)*64 + kk*32 + g*8);
      for (int i = 0; i < 4; ++i)
        for (int j = 0; j < 4; ++j)
          acc[i][j] = mfma_bf16(af[i], bfr[j], acc[i][j]);
    }
    __syncthreads();
  }

  for (int j = 0; j < 4; ++j) {
    const int col = n0 + wc + j*16 + c;
    const float bcol = bias[col];
    for (int i = 0; i < 4; ++i) {
      const int row0 = m0 + wr + i*16 + 4*g;
      for (int r = 0; r < 4; ++r) {
        const size_t idx = (size_t)(row0 + r) * N + col;
        const float v = acc[i][j][r] + bcol;
        if (EPI == 1) {
          const float z = 1.5957691216f * (v + 0.044715f * v * v * v);
          const float e = __expf(z);
          outB[idx] = f2b(v * e * __builtin_amdgcn_rcpf(e + 1.0f));
        } else {
          outF[idx] = v + resid[idx];
        }
      }
    }
  }
}

// ---------------- 256² GEMM, 8-phase interleave, counted vmcnt, swizzled LDS ----------
// 8 waves (2M x 4N), per-wave 128x64. BK=64, 2 K-tiles/iteration, 8 phases.
// Half-tile = 128 rows x 64 cols; staged as 2 x global_load_lds per thread.
// vmcnt(4) only at end of phases 4 and 8 (before the closing barrier).
// EPI 1: gelu -> outB bf16.  EPI 3: qkv scatter (guarded row<MM).
template<int EPI>
__global__ __launch_bounds__(512, 2)
void gemm256(const u16* __restrict__ A, const u16* __restrict__ Bt,
             const float* __restrict__ bias, u16* __restrict__ outB,
             u16* __restrict__ qb, u16* __restrict__ kb, u16* __restrict__ vtb,
             int N, int K, int MT) {
  __shared__ u16 As[2][256*64];
  __shared__ u16 Bs[2][256*64];
  const int tid = threadIdx.x;

  // bijective XCD swizzle (m204)
  const int nwg = gridDim.x;
  const int q8 = nwg >> 3, r8 = nwg & 7;
  const int xcd = blockIdx.x & 7, bidx = blockIdx.x >> 3;
  const int wgid = (xcd < r8 ? xcd * (q8 + 1) : r8 * (q8 + 1) + (xcd - r8) * q8) + bidx;
  const int mb = wgid % MT, nb = wgid / MT;
  const int m0 = mb * 256, n0 = nb * 256;

  const int lane = tid & 63, w = tid >> 6;
  const int wr = w >> 2, wc = w & 3;           // 2 x 4 wave grid
  const int c = lane & 15, g = lane >> 4;
  const int c7 = c & 7;

  // staging geometry: thread covers rows {hf*128+sr, hf*128+sr+64}, source col-group
  // pre-swizzled by row&7 (involution); LDS dest linear per wave (G21).
  const int sr = tid >> 3;          // 0..63
  const int s7 = tid & 7;
  const int scg = s7 ^ (sr & 7);

#define STG_A(bb, tt, hf) do { \
    const int r0_ = (hf)*128 + sr, r1_ = r0_ + 64; \
    gload_lds16(A + (size_t)(m0 + r0_) * K + (size_t)(tt)*64 + scg*8, &As[bb][r0_*64 + s7*8]); \
    gload_lds16(A + (size_t)(m0 + r1_) * K + (size_t)(tt)*64 + scg*8, &As[bb][r1_*64 + s7*8]); \
  } while (0)
#define STG_B(bb, tt, hf) do { \
    const int r0_ = (hf)*128 + sr, r1_ = r0_ + 64; \
    gload_lds16(Bt + (size_t)(n0 + r0_) * K + (size_t)(tt)*64 + scg*8, &Bs[bb][r0_*64 + s7*8]); \
    gload_lds16(Bt + (size_t)(n0 + r1_) * K + (size_t)(tt)*64 + scg*8, &Bs[bb][r1_*64 + s7*8]); \
  } while (0)

  f32x4 acc[8][4];
#pragma unroll
  for (int i = 0; i < 8; ++i)
#pragma unroll
    for (int j = 0; j < 4; ++j) acc[i][j] = f32x4{0.f,0.f,0.f,0.f};

  bf16x8 breg[4][2], areg[2][2];

#define RD_B(bb) do { _Pragma("unroll") \
    for (int nf = 0; nf < 4; ++nf) { _Pragma("unroll") \
      for (int kk = 0; kk < 2; ++kk) { \
        const int row_ = wc*64 + nf*16 + c; \
        const int grp_ = (kk*4 + g) ^ c7; \
        breg[nf][kk] = *(const bf16x8*)(&Bs[bb][row_*64 + grp_*8]); } } } while (0)
#define RD_A(bb, q) do { _Pragma("unroll") \
    for (int mi = 0; mi < 2; ++mi) { _Pragma("unroll") \
      for (int kk = 0; kk < 2; ++kk) { \
        const int row_ = wr*128 + ((q)*2 + mi)*16 + c; \
        const int grp_ = (kk*4 + g) ^ c7; \
        areg[mi][kk] = *(const bf16x8*)(&As[bb][row_*64 + grp_*8]); } } } while (0)
#define DO_MFMA(q) do { __builtin_amdgcn_s_setprio(1); _Pragma("unroll") \
    for (int mi = 0; mi < 2; ++mi) { _Pragma("unroll") \
      for (int nf = 0; nf < 4; ++nf) { _Pragma("unroll") \
        for (int kk = 0; kk < 2; ++kk) \
          acc[(q)*2 + mi][nf] = mfma_bf16(areg[mi][kk], breg[nf][kk], acc[(q)*2 + mi][nf]); } } \
    __builtin_amdgcn_s_setprio(0); } while (0)
#define SYNC1 do { __builtin_amdgcn_sched_barrier(0); __builtin_amdgcn_s_barrier(); \
    asm volatile("s_waitcnt lgkmcnt(0)" ::: "memory"); \
    __builtin_amdgcn_sched_barrier(0); } while (0)
#define SYNC2 do { __builtin_amdgcn_sched_barrier(0); __builtin_amdgcn_s_barrier(); } while (0)

  const int NT = K >> 6;       // K-tiles
  const int NIT = NT >> 1;     // iterations (2 tiles each); K=1024 -> 8

  // prologue: B(T0), A(T0), B(T1) = 12 loads; retire first 8
  STG_B(0, 0, 0); STG_B(0, 0, 1);
  STG_A(0, 0, 0); STG_A(0, 0, 1);
  STG_B(1, 1, 0); STG_B(1, 1, 1);
  __builtin_amdgcn_sched_barrier(0);
  asm volatile("s_waitcnt vmcnt(4)" ::: "memory");
  __builtin_amdgcn_s_barrier();

  for (int it = 0; it < NIT; ++it) {
    const int T0 = 2*it, T1 = T0 + 1;
    const bool last = (it == NIT - 1);
    // P1: buf0 — B-frags + A-q0; stage A-top(T1)->buf1
    RD_B(0); RD_A(0, 0); STG_A(1, T1, 0);
    SYNC1; DO_MFMA(0); SYNC2;
    // P2: A-q1; stage A-bot(T1)->buf1
    RD_A(0, 1); STG_A(1, T1, 1);
    SYNC1; DO_MFMA(1); SYNC2;
    // P3: A-q2; stage B-top(T0+2)->buf0 [B(buf0) free after P1]
    RD_A(0, 2); if (!last) STG_B(0, T0 + 2, 0);
    SYNC1; DO_MFMA(2); SYNC2;
    // P4: A-q3; stage B-bot(T0+2)->buf0; vmcnt gate for buf1 reads
    RD_A(0, 3); if (!last) STG_B(0, T0 + 2, 1);
    SYNC1; DO_MFMA(3);
    __builtin_amdgcn_sched_barrier(0);
    if (last) asm volatile("s_waitcnt vmcnt(0)" ::: "memory");
    else      asm volatile("s_waitcnt vmcnt(4)" ::: "memory");
    __builtin_amdgcn_s_barrier();
    // P5: buf1 — B-frags + A-q0; stage A-top(T0+2)->buf0 [A(buf0) free after P4]
    RD_B(1); RD_A(1, 0); if (!last) STG_A(0, T0 + 2, 0);
    SYNC1; DO_MFMA(0); SYNC2;
    // P6: A-q1; stage A-bot(T0+2)->buf0
    RD_A(1, 1); if (!last) STG_A(0, T0 + 2, 1);
    SYNC1; DO_MFMA(1); SYNC2;
    // P7: A-q2; stage B-top(T1+2)->buf1 [B(buf1) free after P5]
    RD_A(1, 2); if (!last) STG_B(1, T1 + 2, 0);
    SYNC1; DO_MFMA(2); SYNC2;
    // P8: A-q3; stage B-bot(T1+2)->buf1; vmcnt gate for next iter's buf0 reads
    RD_A(1, 3); if (!last) STG_B(1, T1 + 2, 1);
    SYNC1; DO_MFMA(3);
    if (!last) {
      __builtin_amdgcn_sched_barrier(0);
      asm volatile("s_waitcnt vmcnt(4)" ::: "memory");
      __builtin_amdgcn_s_barrier();
    }
  }
#undef STG_A
#undef STG_B
#undef RD_B
#undef RD_A
#undef DO_MFMA
#undef SYNC1
#undef SYNC2

  // epilogue
#pragma unroll
  for (int nf = 0; nf < 4; ++nf) {
    const int col = n0 + wc*64 + nf*16 + c;
    const float bcol = bias[col];
#pragma unroll
    for (int mf = 0; mf < 8; ++mf) {
      const int row0 = m0 + wr*128 + mf*16 + 4*g;
      if (EPI == 3) {
        if (row0 < MM) {
          const int part = col >> 10;
          const int hh2  = (col >> 6) & 15;
          const int hd   = col & 63;
          const int bb   = (int)((unsigned)row0 / SS);
          const int s0   = row0 - bb * SS;
          const size_t bh = (size_t)(bb * HH + hh2);
          if (part == 2) {
            ushort4 pk;
            pk.x = f2b(acc[mf][nf][0] + bcol);
            pk.y = f2b(acc[mf][nf][1] + bcol);
            pk.z = f2b(acc[mf][nf][2] + bcol);
            pk.w = f2b(acc[mf][nf][3] + bcol);
            *(ushort4*)(vtb + (bh*64 + hd)*SP + s0) = pk;
          } else if (part == 0) {
            for (int r = 0; r < 4; ++r)
              qb[(bh*SP + s0 + r)*64 + hd] = f2b((acc[mf][nf][r] + bcol) * 0.125f);
          } else {
            for (int r = 0; r < 4; ++r)
              kb[(bh*SP + s0 + r)*64 + hd] = f2b(acc[mf][nf][r] + bcol);
          }
        }
      } else {
        for (int r = 0; r < 4; ++r) {
          const float v = acc[mf][nf][r] + bcol;
          const float z = 1.5957691216f * (v + 0.044715f * v * v * v);
          const float e = __expf(z);
          outB[(size_t)(row0 + r) * N + col] = f2b(v * e * __builtin_amdgcn_rcpf(e + 1.0f));
        }
      }
    }
  }
}

// ---------------- staged attention + fused tail (r11, unchanged) ----------------------
__global__ __launch_bounds__(512, 8)
void attn_staged(const u16* __restrict__ Qb, const u16* __restrict__ Kb,
                 const u16* __restrict__ VTb, u16* __restrict__ out,
                 const int* __restrict__ npt) {
  __shared__ u16 KV[2][4096];       // per buf: [0..2048) K tile, [2048..4096) V tile
  __shared__ u16 PT[8][640];        // per-wave P^T, 16 rows x 40 u16 (bf16)
  const int tid = threadIdx.x;
  const int w = tid >> 6, lane = tid & 63;
  const int c = lane & 15, g = lane >> 4;
  const int nin = npt[0];
  u16* pw = PT[w];

  if (blockIdx.x < NTAIL) {
    const int bh = blockIdx.x * 8 + w;
    const int b = bh >> 4, hh = bh & 15;
    const int q0 = 64 * 16;

    bf16x8 aq0, aq1;
    {
      const u16* qp = Qb + ((size_t)bh * SP + q0 + c) * 64 + g * 8;
      aq0 = *(const bf16x8*)qp;
      aq1 = *(const bf16x8*)(qp + 32);
    }

    float m[4], ls[4];
    f32x4 o[4];
    int qrow[4];
    for (int r = 0; r < 4; ++r) { m[r] = -1e30f; ls[r] = 0.f; qrow[r] = q0 + 4*g + r; }
    for (int nd = 0; nd < 4; ++nd) o[nd] = f32x4{0.f,0.f,0.f,0.f};

    for (int kt = 0; kt < 33; ++kt) {
      const int k0 = kt * 32;

      f32x4 s[2];
      {
        const u16* kp0 = Kb + ((size_t)bh * SP + k0 + c) * 64 + g * 8;
        f32x4 z0 = f32x4{0.f,0.f,0.f,0.f};
        z0 = mfma_bf16(aq0, *(const bf16x8*)kp0, z0);
        z0 = mfma_bf16(aq1, *(const bf16x8*)(kp0 + 32), z0);
        s[0] = z0;
        const u16* kp1 = kp0 + 16 * 64;
        f32x4 z1 = f32x4{0.f,0.f,0.f,0.f};
        z1 = mfma_bf16(aq0, *(const bf16x8*)kp1, z1);
        z1 = mfma_bf16(aq1, *(const bf16x8*)(kp1 + 32), z1);
        s[1] = z1;
      }

      for (int jt = 0; jt < 2; ++jt) {
        const int j = k0 + jt*16 + c;
        for (int r = 0; r < 4; ++r) {
          const int q = qrow[r];
          const bool blocked = (j >= SS) || ((q >= nin) && (j >= nin) && (j > q));
          if (blocked) s[jt][r] = -1e30f;
        }
      }

      for (int r = 0; r < 4; ++r) {
        float t = fmaxf(s[0][r], s[1][r]);
        for (int off = 1; off < 16; off <<= 1) t = fmaxf(t, __shfl_xor(t, off));
        const float mn = fmaxf(m[r], t);
        const float al = __expf(m[r] - mn);
        m[r] = mn;
        const float p0 = __expf(s[0][r] - mn);
        const float p1 = __expf(s[1][r] - mn);
        s[0][r] = p0; s[1][r] = p1;
        float ps = p0 + p1;
        for (int off = 1; off < 16; off <<= 1) ps += __shfl_xor(ps, off);
        ls[r] = ls[r] * al + ps;
        for (int nd = 0; nd < 4; ++nd) o[nd][r] *= al;
      }

      for (int jt = 0; jt < 2; ++jt)
        for (int r = 0; r < 4; ++r)
          pw[(4*g + r)*40 + jt*16 + c] = f2b(s[jt][r]);
      __builtin_amdgcn_sched_barrier(0);
      bf16x8 ap = *(const bf16x8*)(pw + c*40 + 8*g);
      __builtin_amdgcn_sched_barrier(0);

      for (int nd = 0; nd < 4; ++nd) {
        const u16* vp = VTb + ((size_t)bh * 64 + nd*16 + c) * SP + k0 + 8*g;
        o[nd] = mfma_bf16(ap, *(const bf16x8*)vp, o[nd]);
      }
    }

    for (int nd = 0; nd < 4; ++nd)
      for (int r = 0; r < 4; ++r) {
        const float v = o[nd][r] / ls[r];
        out[((size_t)b * SS + qrow[r]) * DD + hh*64 + nd*16 + c] = f2b(v);
      }
    return;
  }

  // staged path (XCD-grouped bh mapping)
  const int sb = blockIdx.x - NTAIL;
  const int bh = sb & 127;
  const int qt = (sb >> 7) * 8 + w;
  const int b = bh >> 4, hh = bh & 15;
  const int q0 = qt * 16;

  const u16* ssrc; int kstr; u16* sdst;
  if (tid < 256) {
    const int row = tid >> 3, col8 = (tid & 7) ^ (row & 7);
    ssrc = Kb + ((size_t)bh * SP + row) * 64 + col8 * 8;
    kstr = 32 * 64;
    sdst = &KV[0][tid * 8];
  } else {
    const int t2 = tid - 256, row = t2 >> 2, col8 = (t2 & 3) ^ (row & 3);
    ssrc = VTb + ((size_t)bh * 64 + row) * SP + col8 * 8;
    kstr = 32;
    sdst = &KV[0][2048 + t2 * 8];
  }
#define STAGE(bufbit, kt) gload_lds16(ssrc + (size_t)(kt) * kstr, sdst + (bufbit) * 4096)

  bf16x8 aq0, aq1;
  {
    const u16* qp = Qb + ((size_t)bh * SP + q0 + c) * 64 + g * 8;
    aq0 = *(const bf16x8*)qp;
    aq1 = *(const bf16x8*)(qp + 32);
  }

  Bf8 onesf;
  for (int i = 0; i < 8; ++i) onesf.s[i] = (c == 0) ? (u16)0x3F80 : (u16)0;

  float m[4];
  f32x4 o[5];                        // o[4] = ls accumulator (column 0)
  int qrow[4];
  for (int r = 0; r < 4; ++r) { m[r] = -1e30f; qrow[r] = q0 + 4*g + r; }
  for (int nd = 0; nd < 5; ++nd) o[nd] = f32x4{0.f,0.f,0.f,0.f};

  const bool tile_regs = (q0 + 15) >= nin;
  const int c7 = c & 7, c3 = c & 3;

  STAGE(0, 0);

  for (int kt = 0; kt < 33; ++kt) {
    const int buf = kt & 1;
    __syncthreads();
    if (kt < 32) STAGE(buf ^ 1, kt + 1);
    const u16* Kt = &KV[buf][0];
    const u16* Vt = &KV[buf][2048];
    const int k0 = kt * 32;

    f32x4 s[2];
    {
      bf16x8 k00 = *(const bf16x8*)(Kt + c*64        + ((g    ) ^ c7) * 8);
      bf16x8 k01 = *(const bf16x8*)(Kt + c*64        + ((g + 4) ^ c7) * 8);
      f32x4 z0 = f32x4{0.f,0.f,0.f,0.f};
      z0 = mfma_bf16(aq0, k00, z0);
      z0 = mfma_bf16(aq1, k01, z0);
      s[0] = z0;
      bf16x8 k10 = *(const bf16x8*)(Kt + (c+16)*64   + ((g    ) ^ c7) * 8);
      bf16x8 k11 = *(const bf16x8*)(Kt + (c+16)*64   + ((g + 4) ^ c7) * 8);
      f32x4 z1 = f32x4{0.f,0.f,0.f,0.f};
      z1 = mfma_bf16(aq0, k10, z1);
      z1 = mfma_bf16(aq1, k11, z1);
      s[1] = z1;
    }

    if (tile_regs || (k0 + 31 >= SS)) {
      for (int jt = 0; jt < 2; ++jt) {
        const int j = k0 + jt*16 + c;
        for (int r = 0; r < 4; ++r) {
          const int q = qrow[r];
          const bool blocked = (j >= SS) || ((q >= nin) && (j >= nin) && (j > q));
          if (blocked) s[jt][r] = -1e30f;
        }
      }
    }

    for (int r = 0; r < 4; ++r) {
      const float t = dppmax16(fmaxf(s[0][r], s[1][r]));
      const float mn = fmaxf(m[r], t);
      const float al = __expf(m[r] - mn);
      m[r] = mn;
      for (int nd = 0; nd < 5; ++nd) o[nd][r] *= al;
      s[0][r] = __expf(s[0][r] - mn);
      s[1][r] = __expf(s[1][r] - mn);
    }

    for (int jt = 0; jt < 2; ++jt)
      for (int r = 0; r < 4; ++r)
        pw[(4*g + r)*40 + jt*16 + c] = f2b(s[jt][r]);
    __builtin_amdgcn_sched_barrier(0);
    bf16x8 ap = *(const bf16x8*)(pw + c*40 + 8*g);
    __builtin_amdgcn_sched_barrier(0);

    for (int nd = 0; nd < 4; ++nd) {
      bf16x8 bv = *(const bf16x8*)(Vt + (nd*16 + c)*32 + ((g ^ c3) * 8));
      o[nd] = mfma_bf16(ap, bv, o[nd]);
    }
    o[4] = mfma_bf16(ap, onesf.v, o[4]);   // ls accumulates in column 0
  }
#undef STAGE

  float rls[4];
  for (int r = 0; r < 4; ++r)
    rls[r] = 1.0f / __shfl(o[4][r], lane & 48);
  for (int nd = 0; nd < 4; ++nd)
    for (int r = 0; r < 4; ++r)
      out[((size_t)b * SS + qrow[r]) * DD + hh*64 + nd*16 + c] = f2b(o[nd][r] * rls[r]);
}

// ---------------------------------------------------------------------------------------
extern "C" void kernel_launch(void* const* d_in, const int* in_sizes, int n_in,
                              void* d_out, int out_size, void* d_ws, size_t ws_size,
                              hipStream_t stream) {
  const float* x    = (const float*)d_in[0];
  const int*   npt  = (const int*)  d_in[1];
  const float* ln1g = (const float*)d_in[2];
  const float* ln1b = (const float*)d_in[3];
  const float* wqkv = (const float*)d_in[4];
  const float* bqkv = (const float*)d_in[5];
  const float* wo   = (const float*)d_in[6];
  const float* bo   = (const float*)d_in[7];
  const float* ln2g = (const float*)d_in[8];
  const float* ln2b = (const float*)d_in[9];
  const float* w1   = (const float*)d_in[10];
  const float* b1   = (const float*)d_in[11];
  const float* w2   = (const float*)d_in[12];
  const float* b2   = (const float*)d_in[13];
  const float* lnfg = (const float*)d_in[14];
  const float* lnfb = (const float*)d_in[15];

  char* ws = (char*)d_ws;
  size_t off = 0;
  u16*   wqkvT = (u16*)(ws + off);   off += (size_t)NL*TD*DD*2;
  u16*   woT   = (u16*)(ws + off);   off += (size_t)NL*DD*DD*2;
  u16*   w1T   = (u16*)(ws + off);   off += (size_t)NL*DFFN*DD*2;
  u16*   w2T   = (u16*)(ws + off);   off += (size_t)NL*DD*DFFN*2;
  float* h     = (float*)(ws + off); off += (size_t)MM*DD*4;
  u16*   lnb   = (u16*)(ws + off);   off += (size_t)MP*DD*2;
  u16*   Qb    = (u16*)(ws + off);   off += (size_t)BB*HH*SP*64*2;
  u16*   Kb    = (u16*)(ws + off);   off += (size_t)BB*HH*SP*64*2;
  u16*   VTb   = (u16*)(ws + off);   off += (size_t)BB*HH*64*SP*2;
  u16*   attnO = (u16*)(ws + off);   off += (size_t)MM*DD*2;
  u16*   ffh   = (u16*)(ws + off);   off += (size_t)MP*DFFN*2;

  const dim3 tb(32, 8);
  transpose_cast<<<dim3(TD/32,   DD/32,   NL), tb, 0, stream>>>(wqkv, wqkvT, DD,   TD);
  transpose_cast<<<dim3(DD/32,   DD/32,   NL), tb, 0, stream>>>(wo,   woT,   DD,   DD);
  transpose_cast<<<dim3(DFFN/32, DD/32,   NL), tb, 0, stream>>>(w1,   w1T,   DD,   DFFN);
  transpose_cast<<<dim3(DD/32,   DFFN/32, NL), tb, 0, stream>>>(w2,   w2T,   DFFN, DD);
  hipMemcpyAsync(h, x, (size_t)MM*DD*4, hipMemcpyDeviceToDevice, stream);
  hipMemsetAsync(Qb, 0, (size_t)3*BB*HH*SP*64*2, stream);   // zero Q/K/VT arena (pads)

  for (int l = 0; l < NL; ++l) {
    ln_kernel<0><<<MM, 256, 0, stream>>>(h, ln1g + (size_t)l*DD, ln1b + (size_t)l*DD, lnb, nullptr);
    gemm256<3><<<dim3((MP/256)*(TD/256)), 512, 0, stream>>>(
        lnb, wqkvT + (size_t)l*TD*DD, bqkv + (size_t)l*TD, nullptr,
        Qb, Kb, VTb, TD, DD, MP/256);
    attn_staged<<<dim3(BB*HH*8 + NTAIL), 512, 0, stream>>>(Qb, Kb, VTb, attnO, npt);
    gemm_bt<2><<<dim3(MM/128, DD/128), 256, 0, stream>>>(
        attnO, woT + (size_t)l*DD*DD, bo + (size_t)l*DD, h, h, nullptr, DD, DD);
    ln_kernel<0><<<MM, 256, 0, stream>>>(h, ln2g + (size_t)l*DD, ln2b + (size_t)l*DD, lnb, nullptr);
    gemm256<1><<<dim3((MP/256)*(DFFN/256)), 512, 0, stream>>>(
        lnb, w1T + (size_t)l*DFFN*DD, b1 + (size_t)l*DFFN, ffh,
        nullptr, nullptr, nullptr, DFFN, DD, MP/256);
    gemm_bt<2><<<dim3(MM/128, DD/128), 256, 0, stream>>>(
        ffh, w2T + (size_t)l*DD*DFFN, b2 + (size_t)l*DD, h, h, nullptr, DD, DFFN);
  }
  ln_kernel<1><<<MM, 256, 0, stream>>>(h, lnfg, lnfb, nullptr, (float*)d_out);
}

// Round 13
// 6210.659 us; speedup vs baseline: 1.1176x; 1.1176x over previous
//
#include <hip/hip_runtime.h>
#include <hip/hip_bf16.h>
#include <stdint.h>

#define DD   1024
#define TD   3072
#define DFFN 4096
#define NL   12
#define SS   1040
#define SP   1056          /* padded seq for attention operand arena */
#define BB   8
#define MM   (BB*SS)       /* 8320 */
#define HH   16
#define NTAIL 16           /* leading tail blocks in attn_staged grid */

typedef float  f32x4  __attribute__((ext_vector_type(4)));
typedef __bf16 bf16x8 __attribute__((ext_vector_type(8)));
typedef unsigned short u16;

union Bf8 { bf16x8 v; u16 s[8]; };

__device__ __forceinline__ u16 f2b(float f) {
  union { float f; unsigned u; } x; x.f = f;
  unsigned r = (x.u + 0x7FFFu + ((x.u >> 16) & 1u)) >> 16;
  return (u16)r;
}

__device__ __forceinline__ f32x4 mfma_bf16(bf16x8 a, bf16x8 b, f32x4 c) {
  return __builtin_amdgcn_mfma_f32_16x16x32_bf16(a, b, c, 0, 0, 0);
}

__device__ __forceinline__ void gload_lds16(const u16* g, u16* l) {
  __builtin_amdgcn_global_load_lds((const __attribute__((address_space(1))) void*)g,
                                   (__attribute__((address_space(3))) void*)l, 16, 0, 0);
}

// 16-lane max reduce via DPP (quad_perm xor1, xor2, row_ror:4, row_ror:8) — VALU-speed.
__device__ __forceinline__ float dppmax16(float t) {
  union { float f; int i; } u, v;
  u.f = t;
  v.i = __builtin_amdgcn_update_dpp(0, u.i, 0xB1, 0xF, 0xF, true);   // quad_perm [1,0,3,2]
  u.f = fmaxf(u.f, v.f);
  v.i = __builtin_amdgcn_update_dpp(0, u.i, 0x4E, 0xF, 0xF, true);   // quad_perm [2,3,0,1]
  u.f = fmaxf(u.f, v.f);
  v.i = __builtin_amdgcn_update_dpp(0, u.i, 0x124, 0xF, 0xF, true);  // row_ror:4
  u.f = fmaxf(u.f, v.f);
  v.i = __builtin_amdgcn_update_dpp(0, u.i, 0x128, 0xF, 0xF, true);  // row_ror:8
  u.f = fmaxf(u.f, v.f);
  return u.f;
}

// ---------------- weight cast+transpose: in (K,N) f32 -> out (N,K) bf16, per layer z ----
__global__ __launch_bounds__(256)
void transpose_cast(const float* __restrict__ in, u16* __restrict__ out, int K, int N) {
  __shared__ float tile[32][33];
  const int n0 = blockIdx.x * 32, k0 = blockIdx.y * 32;
  const size_t lb = (size_t)blockIdx.z * K * N;
  const int tx = threadIdx.x, ty = threadIdx.y;
  for (int j = 0; j < 4; ++j)
    tile[ty + 8*j][tx] = in[lb + (size_t)(k0 + ty + 8*j) * N + n0 + tx];
  __syncthreads();
  for (int j = 0; j < 4; ++j)
    out[lb + (size_t)(n0 + ty + 8*j) * K + k0 + tx] = f2b(tile[tx][ty + 8*j]);
}

// ---------------- LayerNorm: row of 1024, OUTF=0 -> bf16 out, OUTF=1 -> f32 out --------
template<int OUTF>
__global__ __launch_bounds__(256)
void ln_kernel(const float* __restrict__ in, const float* __restrict__ gam,
               const float* __restrict__ bet, u16* __restrict__ outb, float* __restrict__ outf) {
  const int row = blockIdx.x, t = threadIdx.x;
  const float4 v = ((const float4*)(in + (size_t)row * DD))[t];
  float s  = v.x + v.y + v.z + v.w;
  float s2 = v.x*v.x + v.y*v.y + v.z*v.z + v.w*v.w;
  for (int off = 1; off < 64; off <<= 1) { s += __shfl_xor(s, off); s2 += __shfl_xor(s2, off); }
  __shared__ float red[8];
  if ((t & 63) == 0) { red[t >> 6] = s; red[4 + (t >> 6)] = s2; }
  __syncthreads();
  s  = red[0] + red[1] + red[2] + red[3];
  s2 = red[4] + red[5] + red[6] + red[7];
  const float mu = s * (1.0f/1024.0f);
  const float var = s2 * (1.0f/1024.0f) - mu*mu;
  const float rs = rsqrtf(var + 1e-6f);
  const float4 gv = ((const float4*)gam)[t];
  const float4 bv = ((const float4*)bet)[t];
  const float y0 = (v.x - mu)*rs*gv.x + bv.x;
  const float y1 = (v.y - mu)*rs*gv.y + bv.y;
  const float y2 = (v.z - mu)*rs*gv.z + bv.z;
  const float y3 = (v.w - mu)*rs*gv.w + bv.w;
  if (OUTF) {
    float4 o; o.x=y0; o.y=y1; o.z=y2; o.w=y3;
    ((float4*)(outf + (size_t)row * DD))[t] = o;
  } else {
    ushort4 o; o.x=f2b(y0); o.y=f2b(y1); o.z=f2b(y2); o.w=f2b(y3);
    ((ushort4*)(outb + (size_t)row * DD))[t] = o;
  }
}

// ---------------- GEMM: C(M,N) = A(M,K)bf16 @ Bt(N,K)bf16^T + bias [+ epi] -------------
// EPI 0: write f32.  EPI 1: gelu, write bf16.  EPI 2: +resid, write f32.
// EPI 3: qkv scatter -> Qb (b,h,s,hd) bf16 *0.125, Kb (b,h,s,hd) bf16, VTb (b,h,hd,s) bf16.
// Decode is nb-fastest: consecutive (same-XCD) blocks share the A-panel -> A read once
// per XCD; B (weights, <=8MB/layer) is L3-resident by size.
template<int EPI>
__global__ __launch_bounds__(256, 2)
void gemm_bt(const u16* __restrict__ A, const u16* __restrict__ Bt,
             const float* __restrict__ bias, const float* __restrict__ resid,
             float* outF, u16* outB,
             u16* __restrict__ qb, u16* __restrict__ kb, u16* __restrict__ vtb,
             int N, int K) {
  __shared__ u16 As[128*64];
  __shared__ u16 Bs[128*64];
  const int tid = threadIdx.x;

  // XCD-aware bijective swizzle (nwg % 8 == 0 for all our grids), nb-fastest decode
  const int nwg = gridDim.x * gridDim.y;
  int wgid = blockIdx.y * gridDim.x + blockIdx.x;
  wgid = (wgid & 7) * (nwg >> 3) + (wgid >> 3);
  const int nb = wgid % gridDim.y;
  const int mb = wgid / gridDim.y;
  const int m0 = mb * 128, n0 = nb * 128;

  const int lane = tid & 63, w = tid >> 6;
  const int wr = (w >> 1) * 64, wc = (w & 1) * 64;
  const int c = lane & 15, g = lane >> 4;

  f32x4 acc[4][4];
  for (int i = 0; i < 4; ++i) for (int j = 0; j < 4; ++j) acc[i][j] = f32x4{0.f,0.f,0.f,0.f};

  const int srow = tid >> 3, scg = tid & 7;
  const size_t aoff = (size_t)(m0 + srow) * K + scg * 8;
  const size_t boff = (size_t)(n0 + srow) * K + scg * 8;

  for (int kt = 0; kt < K; kt += 64) {
    for (int it = 0; it < 4; ++it) {
      gload_lds16(A  + aoff + (size_t)it * 32 * K + kt, As + (it*256 + tid) * 8);
      gload_lds16(Bt + boff + (size_t)it * 32 * K + kt, Bs + (it*256 + tid) * 8);
    }
    __syncthreads();
    for (int kk = 0; kk < 2; ++kk) {
      bf16x8 af[4], bfr[4];
      for (int i = 0; i < 4; ++i) af[i]  = *(const bf16x8*)(As + (wr + i*16 + c)*64 + kk*32 + g*8);
      for (int j = 0; j < 4; ++j) bfr[j] = *(const bf16x8*)(Bs + (wc + j*16 + c)*64 + kk*32 + g*8);
      for (int i = 0; i < 4; ++i)
        for (int j = 0; j < 4; ++j)
          acc[i][j] = mfma_bf16(af[i], bfr[j], acc[i][j]);
    }
    __syncthreads();
  }

  for (int j = 0; j < 4; ++j) {
    const int col = n0 + wc + j*16 + c;
    const float bcol = bias[col];
    for (int i = 0; i < 4; ++i) {
      const int row0 = m0 + wr + i*16 + 4*g;
      if (EPI == 3) {
        const int part = col >> 10;
        const int hh2  = (col >> 6) & 15;
        const int hd   = col & 63;
        const int bb   = (int)((unsigned)row0 / SS);
        const int s0   = row0 - bb * SS;          // 4-aligned; never crosses batch
        const size_t bh = (size_t)(bb * HH + hh2);
        if (part == 2) {
          ushort4 pk;
          pk.x = f2b(acc[i][j][0] + bcol);
          pk.y = f2b(acc[i][j][1] + bcol);
          pk.z = f2b(acc[i][j][2] + bcol);
          pk.w = f2b(acc[i][j][3] + bcol);
          *(ushort4*)(vtb + (bh*64 + hd)*SP + s0) = pk;
        } else if (part == 0) {
          for (int r = 0; r < 4; ++r)
            qb[(bh*SP + s0 + r)*64 + hd] = f2b((acc[i][j][r] + bcol) * 0.125f);
        } else {
          for (int r = 0; r < 4; ++r)
            kb[(bh*SP + s0 + r)*64 + hd] = f2b(acc[i][j][r] + bcol);
        }
      } else {
        for (int r = 0; r < 4; ++r) {
          const size_t idx = (size_t)(row0 + r) * N + col;
          const float v = acc[i][j][r] + bcol;
          if (EPI == 0) {
            outF[idx] = v;
          } else if (EPI == 1) {
            // tanh-gelu == v * sigmoid(1.5957691*(v + 0.044715 v^3))
            const float z = 1.5957691216f * (v + 0.044715f * v * v * v);
            const float e = __expf(z);
            outB[idx] = f2b(v * e * __builtin_amdgcn_rcpf(e + 1.0f));
          } else {
            outF[idx] = v + resid[idx];
          }
        }
      }
    }
  }
}

// ---------------- staged attention + fused tail --------------------------------------
// Blocks [0, NTAIL): tail path — wave w handles bh = blockIdx*8+w, q-tile 64, direct loads.
// Blocks [NTAIL, NTAIL+1024): staged path — sb = blockIdx-NTAIL.
//   XCD-grouped: bh = sb & 127, qt = (sb>>7)*8 + w (8 blocks per bh land on one XCD).
// Staged-path softmax: DPP max-reduce; ls accumulated via 5th PV MFMA against a register
// ones-fragment (column 0), no sum-shuffles.
__global__ __launch_bounds__(512, 8)
void attn_staged(const u16* __restrict__ Qb, const u16* __restrict__ Kb,
                 const u16* __restrict__ VTb, u16* __restrict__ out,
                 const int* __restrict__ npt) {
  __shared__ u16 KV[2][4096];       // per buf: [0..2048) K tile, [2048..4096) V tile
  __shared__ u16 PT[8][640];        // per-wave P^T, 16 rows x 40 u16 (bf16)
  const int tid = threadIdx.x;
  const int w = tid >> 6, lane = tid & 63;
  const int c = lane & 15, g = lane >> 4;
  const int nin = npt[0];
  u16* pw = PT[w];

  if (blockIdx.x < NTAIL) {
    // ---------------- tail path: q-tile 64, direct global loads -----------------------
    const int bh = blockIdx.x * 8 + w;
    const int b = bh >> 4, hh = bh & 15;
    const int q0 = 64 * 16;

    bf16x8 aq0, aq1;
    {
      const u16* qp = Qb + ((size_t)bh * SP + q0 + c) * 64 + g * 8;
      aq0 = *(const bf16x8*)qp;
      aq1 = *(const bf16x8*)(qp + 32);
    }

    float m[4], ls[4];
    f32x4 o[4];
    int qrow[4];
    for (int r = 0; r < 4; ++r) { m[r] = -1e30f; ls[r] = 0.f; qrow[r] = q0 + 4*g + r; }
    for (int nd = 0; nd < 4; ++nd) o[nd] = f32x4{0.f,0.f,0.f,0.f};

    for (int kt = 0; kt < 33; ++kt) {
      const int k0 = kt * 32;

      f32x4 s[2];
      {
        const u16* kp0 = Kb + ((size_t)bh * SP + k0 + c) * 64 + g * 8;
        f32x4 z0 = f32x4{0.f,0.f,0.f,0.f};
        z0 = mfma_bf16(aq0, *(const bf16x8*)kp0, z0);
        z0 = mfma_bf16(aq1, *(const bf16x8*)(kp0 + 32), z0);
        s[0] = z0;
        const u16* kp1 = kp0 + 16 * 64;
        f32x4 z1 = f32x4{0.f,0.f,0.f,0.f};
        z1 = mfma_bf16(aq0, *(const bf16x8*)kp1, z1);
        z1 = mfma_bf16(aq1, *(const bf16x8*)(kp1 + 32), z1);
        s[1] = z1;
      }

      for (int jt = 0; jt < 2; ++jt) {
        const int j = k0 + jt*16 + c;
        for (int r = 0; r < 4; ++r) {
          const int q = qrow[r];
          const bool blocked = (j >= SS) || ((q >= nin) && (j >= nin) && (j > q));
          if (blocked) s[jt][r] = -1e30f;
        }
      }

      for (int r = 0; r < 4; ++r) {
        float t = fmaxf(s[0][r], s[1][r]);
        for (int off = 1; off < 16; off <<= 1) t = fmaxf(t, __shfl_xor(t, off));
        const float mn = fmaxf(m[r], t);
        const float al = __expf(m[r] - mn);
        m[r] = mn;
        const float p0 = __expf(s[0][r] - mn);
        const float p1 = __expf(s[1][r] - mn);
        s[0][r] = p0; s[1][r] = p1;
        float ps = p0 + p1;
        for (int off = 1; off < 16; off <<= 1) ps += __shfl_xor(ps, off);
        ls[r] = ls[r] * al + ps;
        for (int nd = 0; nd < 4; ++nd) o[nd][r] *= al;
      }

      for (int jt = 0; jt < 2; ++jt)
        for (int r = 0; r < 4; ++r)
          pw[(4*g + r)*40 + jt*16 + c] = f2b(s[jt][r]);
      __builtin_amdgcn_sched_barrier(0);
      bf16x8 ap = *(const bf16x8*)(pw + c*40 + 8*g);
      __builtin_amdgcn_sched_barrier(0);

      for (int nd = 0; nd < 4; ++nd) {
        const u16* vp = VTb + ((size_t)bh * 64 + nd*16 + c) * SP + k0 + 8*g;
        o[nd] = mfma_bf16(ap, *(const bf16x8*)vp, o[nd]);
      }
    }

    for (int nd = 0; nd < 4; ++nd)
      for (int r = 0; r < 4; ++r) {
        const float v = o[nd][r] / ls[r];
        out[((size_t)b * SS + qrow[r]) * DD + hh*64 + nd*16 + c] = f2b(v);
      }
    return;
  }

  // ---------------- staged path (XCD-grouped bh mapping) ----------------
  const int sb = blockIdx.x - NTAIL;
  const int bh = sb & 127;
  const int qt = (sb >> 7) * 8 + w;
  const int b = bh >> 4, hh = bh & 15;
  const int q0 = qt * 16;

  const u16* ssrc; int kstr; u16* sdst;
  if (tid < 256) {
    const int row = tid >> 3, col8 = (tid & 7) ^ (row & 7);
    ssrc = Kb + ((size_t)bh * SP + row) * 64 + col8 * 8;
    kstr = 32 * 64;
    sdst = &KV[0][tid * 8];
  } else {
    const int t2 = tid - 256, row = t2 >> 2, col8 = (t2 & 3) ^ (row & 3);
    ssrc = VTb + ((size_t)bh * 64 + row) * SP + col8 * 8;
    kstr = 32;
    sdst = &KV[0][2048 + t2 * 8];
  }
#define STAGE(bufbit, kt) gload_lds16(ssrc + (size_t)(kt) * kstr, sdst + (bufbit) * 4096)

  bf16x8 aq0, aq1;
  {
    const u16* qp = Qb + ((size_t)bh * SP + q0 + c) * 64 + g * 8;
    aq0 = *(const bf16x8*)qp;
    aq1 = *(const bf16x8*)(qp + 32);
  }

  Bf8 onesf;
  for (int i = 0; i < 8; ++i) onesf.s[i] = (c == 0) ? (u16)0x3F80 : (u16)0;

  float m[4];
  f32x4 o[5];                        // o[4] = ls accumulator (column 0)
  int qrow[4];
  for (int r = 0; r < 4; ++r) { m[r] = -1e30f; qrow[r] = q0 + 4*g + r; }
  for (int nd = 0; nd < 5; ++nd) o[nd] = f32x4{0.f,0.f,0.f,0.f};

  const bool tile_regs = (q0 + 15) >= nin;
  const int c7 = c & 7, c3 = c & 3;

  STAGE(0, 0);

  for (int kt = 0; kt < 33; ++kt) {
    const int buf = kt & 1;
    __syncthreads();                   // buf staged (drains vmcnt) + prior-buf reads done
    if (kt < 32) STAGE(buf ^ 1, kt + 1);
    const u16* Kt = &KV[buf][0];
    const u16* Vt = &KV[buf][2048];
    const int k0 = kt * 32;

    f32x4 s[2];
    {
      bf16x8 k00 = *(const bf16x8*)(Kt + c*64        + ((g    ) ^ c7) * 8);
      bf16x8 k01 = *(const bf16x8*)(Kt + c*64        + ((g + 4) ^ c7) * 8);
      f32x4 z0 = f32x4{0.f,0.f,0.f,0.f};
      z0 = mfma_bf16(aq0, k00, z0);
      z0 = mfma_bf16(aq1, k01, z0);
      s[0] = z0;
      bf16x8 k10 = *(const bf16x8*)(Kt + (c+16)*64   + ((g    ) ^ c7) * 8);
      bf16x8 k11 = *(const bf16x8*)(Kt + (c+16)*64   + ((g + 4) ^ c7) * 8);
      f32x4 z1 = f32x4{0.f,0.f,0.f,0.f};
      z1 = mfma_bf16(aq0, k10, z1);
      z1 = mfma_bf16(aq1, k11, z1);
      s[1] = z1;
    }

    if (tile_regs || (k0 + 31 >= SS)) {
      for (int jt = 0; jt < 2; ++jt) {
        const int j = k0 + jt*16 + c;
        for (int r = 0; r < 4; ++r) {
          const int q = qrow[r];
          const bool blocked = (j >= SS) || ((q >= nin) && (j >= nin) && (j > q));
          if (blocked) s[jt][r] = -1e30f;
        }
      }
    }

    for (int r = 0; r < 4; ++r) {
      const float t = dppmax16(fmaxf(s[0][r], s[1][r]));
      const float mn = fmaxf(m[r], t);
      const float al = __expf(m[r] - mn);
      m[r] = mn;
      for (int nd = 0; nd < 5; ++nd) o[nd][r] *= al;
      s[0][r] = __expf(s[0][r] - mn);
      s[1][r] = __expf(s[1][r] - mn);
    }

    for (int jt = 0; jt < 2; ++jt)
      for (int r = 0; r < 4; ++r)
        pw[(4*g + r)*40 + jt*16 + c] = f2b(s[jt][r]);
    __builtin_amdgcn_sched_barrier(0);
    bf16x8 ap = *(const bf16x8*)(pw + c*40 + 8*g);
    __builtin_amdgcn_sched_barrier(0);

    for (int nd = 0; nd < 4; ++nd) {
      bf16x8 bv = *(const bf16x8*)(Vt + (nd*16 + c)*32 + ((g ^ c3) * 8));
      o[nd] = mfma_bf16(ap, bv, o[nd]);
    }
    o[4] = mfma_bf16(ap, onesf.v, o[4]);   // ls accumulates in column 0
  }
#undef STAGE

  float rls[4];
  for (int r = 0; r < 4; ++r)
    rls[r] = 1.0f / __shfl(o[4][r], lane & 48);   // broadcast ls from c==0 lane of group
  for (int nd = 0; nd < 4; ++nd)
    for (int r = 0; r < 4; ++r)
      out[((size_t)b * SS + qrow[r]) * DD + hh*64 + nd*16 + c] = f2b(o[nd][r] * rls[r]);
}

// ---------------------------------------------------------------------------------------
extern "C" void kernel_launch(void* const* d_in, const int* in_sizes, int n_in,
                              void* d_out, int out_size, void* d_ws, size_t ws_size,
                              hipStream_t stream) {
  const float* x    = (const float*)d_in[0];
  const int*   npt  = (const int*)  d_in[1];
  const float* ln1g = (const float*)d_in[2];
  const float* ln1b = (const float*)d_in[3];
  const float* wqkv = (const float*)d_in[4];
  const float* bqkv = (const float*)d_in[5];
  const float* wo   = (const float*)d_in[6];
  const float* bo   = (const float*)d_in[7];
  const float* ln2g = (const float*)d_in[8];
  const float* ln2b = (const float*)d_in[9];
  const float* w1   = (const float*)d_in[10];
  const float* b1   = (const float*)d_in[11];
  const float* w2   = (const float*)d_in[12];
  const float* b2   = (const float*)d_in[13];
  const float* lnfg = (const float*)d_in[14];
  const float* lnfb = (const float*)d_in[15];

  char* ws = (char*)d_ws;
  size_t off = 0;
  u16*   wqkvT = (u16*)(ws + off);   off += (size_t)NL*TD*DD*2;
  u16*   woT   = (u16*)(ws + off);   off += (size_t)NL*DD*DD*2;
  u16*   w1T   = (u16*)(ws + off);   off += (size_t)NL*DFFN*DD*2;
  u16*   w2T   = (u16*)(ws + off);   off += (size_t)NL*DD*DFFN*2;
  float* h     = (float*)(ws + off); off += (size_t)MM*DD*4;
  u16*   lnb   = (u16*)(ws + off);   off += (size_t)MM*DD*2;
  u16*   Qb    = (u16*)(ws + off);   off += (size_t)BB*HH*SP*64*2;
  u16*   Kb    = (u16*)(ws + off);   off += (size_t)BB*HH*SP*64*2;
  u16*   VTb   = (u16*)(ws + off);   off += (size_t)BB*HH*64*SP*2;
  u16*   attnO = (u16*)(ws + off);   off += (size_t)MM*DD*2;
  u16*   ffh   = (u16*)(ws + off);   off += (size_t)MM*DFFN*2;

  const dim3 tb(32, 8);
  transpose_cast<<<dim3(TD/32,   DD/32,   NL), tb, 0, stream>>>(wqkv, wqkvT, DD,   TD);
  transpose_cast<<<dim3(DD/32,   DD/32,   NL), tb, 0, stream>>>(wo,   woT,   DD,   DD);
  transpose_cast<<<dim3(DFFN/32, DD/32,   NL), tb, 0, stream>>>(w1,   w1T,   DD,   DFFN);
  transpose_cast<<<dim3(DD/32,   DFFN/32, NL), tb, 0, stream>>>(w2,   w2T,   DFFN, DD);
  hipMemcpyAsync(h, x, (size_t)MM*DD*4, hipMemcpyDeviceToDevice, stream);
  hipMemsetAsync(Qb, 0, (size_t)3*BB*HH*SP*64*2, stream);   // zero Q/K/VT arena (pads)

  for (int l = 0; l < NL; ++l) {
    ln_kernel<0><<<MM, 256, 0, stream>>>(h, ln1g + (size_t)l*DD, ln1b + (size_t)l*DD, lnb, nullptr);
    gemm_bt<3><<<dim3(MM/128, TD/128), 256, 0, stream>>>(
        lnb, wqkvT + (size_t)l*TD*DD, bqkv + (size_t)l*TD, nullptr, nullptr, nullptr,
        Qb, Kb, VTb, TD, DD);
    attn_staged<<<dim3(BB*HH*8 + NTAIL), 512, 0, stream>>>(Qb, Kb, VTb, attnO, npt);
    gemm_bt<2><<<dim3(MM/128, DD/128), 256, 0, stream>>>(
        attnO, woT + (size_t)l*DD*DD, bo + (size_t)l*DD, h, h, nullptr,
        nullptr, nullptr, nullptr, DD, DD);
    ln_kernel<0><<<MM, 256, 0, stream>>>(h, ln2g + (size_t)l*DD, ln2b + (size_t)l*DD, lnb, nullptr);
    gemm_bt<1><<<dim3(MM/128, DFFN/128), 256, 0, stream>>>(
        lnb, w1T + (size_t)l*DFFN*DD, b1 + (size_t)l*DFFN, nullptr, nullptr, ffh,
        nullptr, nullptr, nullptr, DFFN, DD);
    gemm_bt<2><<<dim3(MM/128, DD/128), 256, 0, stream>>>(
        ffh, w2T + (size_t)l*DD*DFFN, b2 + (size_t)l*DD, h, h, nullptr,
        nullptr, nullptr, nullptr, DD, DFFN);
  }
  ln_kernel<1><<<MM, 256, 0, stream>>>(h, lnfg, lnfb, nullptr, (float*)d_out);
}

// Round 14
// 6156.401 us; speedup vs baseline: 1.1275x; 1.0088x over previous
//
#include <hip/hip_runtime.h>
#include <hip/hip_bf16.h>
#include <stdint.h>

#define DD   1024
#define TD   3072
#define DFFN 4096
#define NL   12
#define SS   1040
#define SP   1056          /* padded seq for attention operand arena */
#define BB   8
#define MM   (BB*SS)       /* 8320 */
#define HH   16
#define NTAIL 16           /* leading tail blocks in attn_staged grid */

typedef float  f32x4  __attribute__((ext_vector_type(4)));
typedef __bf16 bf16x8 __attribute__((ext_vector_type(8)));
typedef unsigned short u16;

union Bf8 { bf16x8 v; u16 s[8]; };

__device__ __forceinline__ u16 f2b(float f) {
  union { float f; unsigned u; } x; x.f = f;
  unsigned r = (x.u + 0x7FFFu + ((x.u >> 16) & 1u)) >> 16;
  return (u16)r;
}

__device__ __forceinline__ f32x4 mfma_bf16(bf16x8 a, bf16x8 b, f32x4 c) {
  return __builtin_amdgcn_mfma_f32_16x16x32_bf16(a, b, c, 0, 0, 0);
}

__device__ __forceinline__ void gload_lds16(const u16* g, u16* l) {
  __builtin_amdgcn_global_load_lds((const __attribute__((address_space(1))) void*)g,
                                   (__attribute__((address_space(3))) void*)l, 16, 0, 0);
}

// 16-lane max reduce via DPP (quad_perm xor1, xor2, row_ror:4, row_ror:8) — VALU-speed.
__device__ __forceinline__ float dppmax16(float t) {
  union { float f; int i; } u, v;
  u.f = t;
  v.i = __builtin_amdgcn_update_dpp(0, u.i, 0xB1, 0xF, 0xF, true);   // quad_perm [1,0,3,2]
  u.f = fmaxf(u.f, v.f);
  v.i = __builtin_amdgcn_update_dpp(0, u.i, 0x4E, 0xF, 0xF, true);   // quad_perm [2,3,0,1]
  u.f = fmaxf(u.f, v.f);
  v.i = __builtin_amdgcn_update_dpp(0, u.i, 0x124, 0xF, 0xF, true);  // row_ror:4
  u.f = fmaxf(u.f, v.f);
  v.i = __builtin_amdgcn_update_dpp(0, u.i, 0x128, 0xF, 0xF, true);  // row_ror:8
  u.f = fmaxf(u.f, v.f);
  return u.f;
}

// ---------------- weight cast+transpose: in (K,N) f32 -> out (N,K) bf16, per layer z ----
__global__ __launch_bounds__(256)
void transpose_cast(const float* __restrict__ in, u16* __restrict__ out, int K, int N) {
  __shared__ float tile[32][33];
  const int n0 = blockIdx.x * 32, k0 = blockIdx.y * 32;
  const size_t lb = (size_t)blockIdx.z * K * N;
  const int tx = threadIdx.x, ty = threadIdx.y;
  for (int j = 0; j < 4; ++j)
    tile[ty + 8*j][tx] = in[lb + (size_t)(k0 + ty + 8*j) * N + n0 + tx];
  __syncthreads();
  for (int j = 0; j < 4; ++j)
    out[lb + (size_t)(n0 + ty + 8*j) * K + k0 + tx] = f2b(tile[tx][ty + 8*j]);
}

// ---------------- LayerNorm: row of 1024, OUTF=0 -> bf16 out, OUTF=1 -> f32 out --------
template<int OUTF>
__global__ __launch_bounds__(256)
void ln_kernel(const float* __restrict__ in, const float* __restrict__ gam,
               const float* __restrict__ bet, u16* __restrict__ outb, float* __restrict__ outf) {
  const int row = blockIdx.x, t = threadIdx.x;
  const float4 v = ((const float4*)(in + (size_t)row * DD))[t];
  float s  = v.x + v.y + v.z + v.w;
  float s2 = v.x*v.x + v.y*v.y + v.z*v.z + v.w*v.w;
  for (int off = 1; off < 64; off <<= 1) { s += __shfl_xor(s, off); s2 += __shfl_xor(s2, off); }
  __shared__ float red[8];
  if ((t & 63) == 0) { red[t >> 6] = s; red[4 + (t >> 6)] = s2; }
  __syncthreads();
  s  = red[0] + red[1] + red[2] + red[3];
  s2 = red[4] + red[5] + red[6] + red[7];
  const float mu = s * (1.0f/1024.0f);
  const float var = s2 * (1.0f/1024.0f) - mu*mu;
  const float rs = rsqrtf(var + 1e-6f);
  const float4 gv = ((const float4*)gam)[t];
  const float4 bv = ((const float4*)bet)[t];
  const float y0 = (v.x - mu)*rs*gv.x + bv.x;
  const float y1 = (v.y - mu)*rs*gv.y + bv.y;
  const float y2 = (v.z - mu)*rs*gv.z + bv.z;
  const float y3 = (v.w - mu)*rs*gv.w + bv.w;
  if (OUTF) {
    float4 o; o.x=y0; o.y=y1; o.z=y2; o.w=y3;
    ((float4*)(outf + (size_t)row * DD))[t] = o;
  } else {
    ushort4 o; o.x=f2b(y0); o.y=f2b(y1); o.z=f2b(y2); o.w=f2b(y3);
    ((ushort4*)(outb + (size_t)row * DD))[t] = o;
  }
}

// ---------------- GEMM: C(M,N) = A(M,K)bf16 @ Bt(N,K)bf16^T + bias [+ epi] -------------
// EPI 1: gelu, write bf16.  EPI 3: qkv scatter.
// nb-fastest decode: consecutive (same-XCD) blocks share the A-panel.
template<int EPI>
__global__ __launch_bounds__(256, 2)
void gemm_bt(const u16* __restrict__ A, const u16* __restrict__ Bt,
             const float* __restrict__ bias,
             u16* outB,
             u16* __restrict__ qb, u16* __restrict__ kb, u16* __restrict__ vtb,
             int N, int K) {
  __shared__ u16 As[128*64];
  __shared__ u16 Bs[128*64];
  const int tid = threadIdx.x;

  const int nwg = gridDim.x * gridDim.y;
  int wgid = blockIdx.y * gridDim.x + blockIdx.x;
  wgid = (wgid & 7) * (nwg >> 3) + (wgid >> 3);
  const int nb = wgid % gridDim.y;
  const int mb = wgid / gridDim.y;
  const int m0 = mb * 128, n0 = nb * 128;

  const int lane = tid & 63, w = tid >> 6;
  const int wr = (w >> 1) * 64, wc = (w & 1) * 64;
  const int c = lane & 15, g = lane >> 4;

  f32x4 acc[4][4];
  for (int i = 0; i < 4; ++i) for (int j = 0; j < 4; ++j) acc[i][j] = f32x4{0.f,0.f,0.f,0.f};

  const int srow = tid >> 3, scg = tid & 7;
  const size_t aoff = (size_t)(m0 + srow) * K + scg * 8;
  const size_t boff = (size_t)(n0 + srow) * K + scg * 8;

  for (int kt = 0; kt < K; kt += 64) {
    for (int it = 0; it < 4; ++it) {
      gload_lds16(A  + aoff + (size_t)it * 32 * K + kt, As + (it*256 + tid) * 8);
      gload_lds16(Bt + boff + (size_t)it * 32 * K + kt, Bs + (it*256 + tid) * 8);
    }
    __syncthreads();
    for (int kk = 0; kk < 2; ++kk) {
      bf16x8 af[4], bfr[4];
      for (int i = 0; i < 4; ++i) af[i]  = *(const bf16x8*)(As + (wr + i*16 + c)*64 + kk*32 + g*8);
      for (int j = 0; j < 4; ++j) bfr[j] = *(const bf16x8*)(Bs + (wc + j*16 + c)*64 + kk*32 + g*8);
      for (int i = 0; i < 4; ++i)
        for (int j = 0; j < 4; ++j)
          acc[i][j] = mfma_bf16(af[i], bfr[j], acc[i][j]);
    }
    __syncthreads();
  }

  for (int j = 0; j < 4; ++j) {
    const int col = n0 + wc + j*16 + c;
    const float bcol = bias[col];
    for (int i = 0; i < 4; ++i) {
      const int row0 = m0 + wr + i*16 + 4*g;
      if (EPI == 3) {
        const int part = col >> 10;
        const int hh2  = (col >> 6) & 15;
        const int hd   = col & 63;
        const int bb   = (int)((unsigned)row0 / SS);
        const int s0   = row0 - bb * SS;          // 4-aligned; never crosses batch
        const size_t bh = (size_t)(bb * HH + hh2);
        if (part == 2) {
          ushort4 pk;
          pk.x = f2b(acc[i][j][0] + bcol);
          pk.y = f2b(acc[i][j][1] + bcol);
          pk.z = f2b(acc[i][j][2] + bcol);
          pk.w = f2b(acc[i][j][3] + bcol);
          *(ushort4*)(vtb + (bh*64 + hd)*SP + s0) = pk;
        } else if (part == 0) {
          for (int r = 0; r < 4; ++r)
            qb[(bh*SP + s0 + r)*64 + hd] = f2b((acc[i][j][r] + bcol) * 0.125f);
        } else {
          for (int r = 0; r < 4; ++r)
            kb[(bh*SP + s0 + r)*64 + hd] = f2b(acc[i][j][r] + bcol);
        }
      } else {
        for (int r = 0; r < 4; ++r) {
          const size_t idx = (size_t)(row0 + r) * N + col;
          const float v = acc[i][j][r] + bcol;
          const float z = 1.5957691216f * (v + 0.044715f * v * v * v);
          const float e = __expf(z);
          outB[idx] = f2b(v * e * __builtin_amdgcn_rcpf(e + 1.0f));
        }
      }
    }
  }
}

// ---------------- 64x128-tile GEMM for N=1024 shapes (WO, FFN2): +resid, f32 out ------
// 4 waves (2M x 2N of 32x64), grid (M/64) x (N/128) = 130 x 8 = 1040 blocks.
__global__ __launch_bounds__(256, 4)
void gemm64(const u16* __restrict__ A, const u16* __restrict__ Bt,
            const float* __restrict__ bias, const float* __restrict__ resid,
            float* __restrict__ outF, int N, int K) {
  __shared__ u16 As[64*64];
  __shared__ u16 Bs[128*64];
  const int tid = threadIdx.x;

  const int nwg = gridDim.x * gridDim.y;
  int wgid = blockIdx.y * gridDim.x + blockIdx.x;
  wgid = (wgid & 7) * (nwg >> 3) + (wgid >> 3);
  const int nb = wgid % gridDim.y;
  const int mb = wgid / gridDim.y;
  const int m0 = mb * 64, n0 = nb * 128;

  const int lane = tid & 63, w = tid >> 6;
  const int wr = (w >> 1) * 32, wc = (w & 1) * 64;
  const int c = lane & 15, g = lane >> 4;

  f32x4 acc[2][4];
  for (int i = 0; i < 2; ++i) for (int j = 0; j < 4; ++j) acc[i][j] = f32x4{0.f,0.f,0.f,0.f};

  const int srow = tid >> 3, scg = tid & 7;
  const size_t aoff = (size_t)(m0 + srow) * K + scg * 8;
  const size_t boff = (size_t)(n0 + srow) * K + scg * 8;

  for (int kt = 0; kt < K; kt += 64) {
    for (int it = 0; it < 2; ++it)
      gload_lds16(A  + aoff + (size_t)it * 32 * K + kt, As + (it*256 + tid) * 8);
    for (int it = 0; it < 4; ++it)
      gload_lds16(Bt + boff + (size_t)it * 32 * K + kt, Bs + (it*256 + tid) * 8);
    __syncthreads();
    for (int kk = 0; kk < 2; ++kk) {
      bf16x8 af[2], bfr[4];
      for (int i = 0; i < 2; ++i) af[i]  = *(const bf16x8*)(As + (wr + i*16 + c)*64 + kk*32 + g*8);
      for (int j = 0; j < 4; ++j) bfr[j] = *(const bf16x8*)(Bs + (wc + j*16 + c)*64 + kk*32 + g*8);
      for (int i = 0; i < 2; ++i)
        for (int j = 0; j < 4; ++j)
          acc[i][j] = mfma_bf16(af[i], bfr[j], acc[i][j]);
    }
    __syncthreads();
  }

  for (int j = 0; j < 4; ++j) {
    const int col = n0 + wc + j*16 + c;
    const float bcol = bias[col];
    for (int i = 0; i < 2; ++i) {
      const int row0 = m0 + wr + i*16 + 4*g;
      for (int r = 0; r < 4; ++r) {
        const size_t idx = (size_t)(row0 + r) * N + col;
        outF[idx] = acc[i][j][r] + bcol + resid[idx];
      }
    }
  }
}

// ---------------- staged attention + fused tail (r11/r13, unchanged) ------------------
__global__ __launch_bounds__(512, 8)
void attn_staged(const u16* __restrict__ Qb, const u16* __restrict__ Kb,
                 const u16* __restrict__ VTb, u16* __restrict__ out,
                 const int* __restrict__ npt) {
  __shared__ u16 KV[2][4096];       // per buf: [0..2048) K tile, [2048..4096) V tile
  __shared__ u16 PT[8][640];        // per-wave P^T, 16 rows x 40 u16 (bf16)
  const int tid = threadIdx.x;
  const int w = tid >> 6, lane = tid & 63;
  const int c = lane & 15, g = lane >> 4;
  const int nin = npt[0];
  u16* pw = PT[w];

  if (blockIdx.x < NTAIL) {
    const int bh = blockIdx.x * 8 + w;
    const int b = bh >> 4, hh = bh & 15;
    const int q0 = 64 * 16;

    bf16x8 aq0, aq1;
    {
      const u16* qp = Qb + ((size_t)bh * SP + q0 + c) * 64 + g * 8;
      aq0 = *(const bf16x8*)qp;
      aq1 = *(const bf16x8*)(qp + 32);
    }

    float m[4], ls[4];
    f32x4 o[4];
    int qrow[4];
    for (int r = 0; r < 4; ++r) { m[r] = -1e30f; ls[r] = 0.f; qrow[r] = q0 + 4*g + r; }
    for (int nd = 0; nd < 4; ++nd) o[nd] = f32x4{0.f,0.f,0.f,0.f};

    for (int kt = 0; kt < 33; ++kt) {
      const int k0 = kt * 32;

      f32x4 s[2];
      {
        const u16* kp0 = Kb + ((size_t)bh * SP + k0 + c) * 64 + g * 8;
        f32x4 z0 = f32x4{0.f,0.f,0.f,0.f};
        z0 = mfma_bf16(aq0, *(const bf16x8*)kp0, z0);
        z0 = mfma_bf16(aq1, *(const bf16x8*)(kp0 + 32), z0);
        s[0] = z0;
        const u16* kp1 = kp0 + 16 * 64;
        f32x4 z1 = f32x4{0.f,0.f,0.f,0.f};
        z1 = mfma_bf16(aq0, *(const bf16x8*)kp1, z1);
        z1 = mfma_bf16(aq1, *(const bf16x8*)(kp1 + 32), z1);
        s[1] = z1;
      }

      for (int jt = 0; jt < 2; ++jt) {
        const int j = k0 + jt*16 + c;
        for (int r = 0; r < 4; ++r) {
          const int q = qrow[r];
          const bool blocked = (j >= SS) || ((q >= nin) && (j >= nin) && (j > q));
          if (blocked) s[jt][r] = -1e30f;
        }
      }

      for (int r = 0; r < 4; ++r) {
        float t = fmaxf(s[0][r], s[1][r]);
        for (int off = 1; off < 16; off <<= 1) t = fmaxf(t, __shfl_xor(t, off));
        const float mn = fmaxf(m[r], t);
        const float al = __expf(m[r] - mn);
        m[r] = mn;
        const float p0 = __expf(s[0][r] - mn);
        const float p1 = __expf(s[1][r] - mn);
        s[0][r] = p0; s[1][r] = p1;
        float ps = p0 + p1;
        for (int off = 1; off < 16; off <<= 1) ps += __shfl_xor(ps, off);
        ls[r] = ls[r] * al + ps;
        for (int nd = 0; nd < 4; ++nd) o[nd][r] *= al;
      }

      for (int jt = 0; jt < 2; ++jt)
        for (int r = 0; r < 4; ++r)
          pw[(4*g + r)*40 + jt*16 + c] = f2b(s[jt][r]);
      __builtin_amdgcn_sched_barrier(0);
      bf16x8 ap = *(const bf16x8*)(pw + c*40 + 8*g);
      __builtin_amdgcn_sched_barrier(0);

      for (int nd = 0; nd < 4; ++nd) {
        const u16* vp = VTb + ((size_t)bh * 64 + nd*16 + c) * SP + k0 + 8*g;
        o[nd] = mfma_bf16(ap, *(const bf16x8*)vp, o[nd]);
      }
    }

    for (int nd = 0; nd < 4; ++nd)
      for (int r = 0; r < 4; ++r) {
        const float v = o[nd][r] / ls[r];
        out[((size_t)b * SS + qrow[r]) * DD + hh*64 + nd*16 + c] = f2b(v);
      }
    return;
  }

  // staged path (XCD-grouped bh mapping)
  const int sb = blockIdx.x - NTAIL;
  const int bh = sb & 127;
  const int qt = (sb >> 7) * 8 + w;
  const int b = bh >> 4, hh = bh & 15;
  const int q0 = qt * 16;

  const u16* ssrc; int kstr; u16* sdst;
  if (tid < 256) {
    const int row = tid >> 3, col8 = (tid & 7) ^ (row & 7);
    ssrc = Kb + ((size_t)bh * SP + row) * 64 + col8 * 8;
    kstr = 32 * 64;
    sdst = &KV[0][tid * 8];
  } else {
    const int t2 = tid - 256, row = t2 >> 2, col8 = (t2 & 3) ^ (row & 3);
    ssrc = VTb + ((size_t)bh * 64 + row) * SP + col8 * 8;
    kstr = 32;
    sdst = &KV[0][2048 + t2 * 8];
  }
#define STAGE(bufbit, kt) gload_lds16(ssrc + (size_t)(kt) * kstr, sdst + (bufbit) * 4096)

  bf16x8 aq0, aq1;
  {
    const u16* qp = Qb + ((size_t)bh * SP + q0 + c) * 64 + g * 8;
    aq0 = *(const bf16x8*)qp;
    aq1 = *(const bf16x8*)(qp + 32);
  }

  Bf8 onesf;
  for (int i = 0; i < 8; ++i) onesf.s[i] = (c == 0) ? (u16)0x3F80 : (u16)0;

  float m[4];
  f32x4 o[5];                        // o[4] = ls accumulator (column 0)
  int qrow[4];
  for (int r = 0; r < 4; ++r) { m[r] = -1e30f; qrow[r] = q0 + 4*g + r; }
  for (int nd = 0; nd < 5; ++nd) o[nd] = f32x4{0.f,0.f,0.f,0.f};

  const bool tile_regs = (q0 + 15) >= nin;
  const int c7 = c & 7, c3 = c & 3;

  STAGE(0, 0);

  for (int kt = 0; kt < 33; ++kt) {
    const int buf = kt & 1;
    __syncthreads();                   // buf staged (drains vmcnt) + prior-buf reads done
    if (kt < 32) STAGE(buf ^ 1, kt + 1);
    const u16* Kt = &KV[buf][0];
    const u16* Vt = &KV[buf][2048];
    const int k0 = kt * 32;

    f32x4 s[2];
    {
      bf16x8 k00 = *(const bf16x8*)(Kt + c*64        + ((g    ) ^ c7) * 8);
      bf16x8 k01 = *(const bf16x8*)(Kt + c*64        + ((g + 4) ^ c7) * 8);
      f32x4 z0 = f32x4{0.f,0.f,0.f,0.f};
      z0 = mfma_bf16(aq0, k00, z0);
      z0 = mfma_bf16(aq1, k01, z0);
      s[0] = z0;
      bf16x8 k10 = *(const bf16x8*)(Kt + (c+16)*64   + ((g    ) ^ c7) * 8);
      bf16x8 k11 = *(const bf16x8*)(Kt + (c+16)*64   + ((g + 4) ^ c7) * 8);
      f32x4 z1 = f32x4{0.f,0.f,0.f,0.f};
      z1 = mfma_bf16(aq0, k10, z1);
      z1 = mfma_bf16(aq1, k11, z1);
      s[1] = z1;
    }

    if (tile_regs || (k0 + 31 >= SS)) {
      for (int jt = 0; jt < 2; ++jt) {
        const int j = k0 + jt*16 + c;
        for (int r = 0; r < 4; ++r) {
          const int q = qrow[r];
          const bool blocked = (j >= SS) || ((q >= nin) && (j >= nin) && (j > q));
          if (blocked) s[jt][r] = -1e30f;
        }
      }
    }

    for (int r = 0; r < 4; ++r) {
      const float t = dppmax16(fmaxf(s[0][r], s[1][r]));
      const float mn = fmaxf(m[r], t);
      const float al = __expf(m[r] - mn);
      m[r] = mn;
      for (int nd = 0; nd < 5; ++nd) o[nd][r] *= al;
      s[0][r] = __expf(s[0][r] - mn);
      s[1][r] = __expf(s[1][r] - mn);
    }

    for (int jt = 0; jt < 2; ++jt)
      for (int r = 0; r < 4; ++r)
        pw[(4*g + r)*40 + jt*16 + c] = f2b(s[jt][r]);
    __builtin_amdgcn_sched_barrier(0);
    bf16x8 ap = *(const bf16x8*)(pw + c*40 + 8*g);
    __builtin_amdgcn_sched_barrier(0);

    for (int nd = 0; nd < 4; ++nd) {
      bf16x8 bv = *(const bf16x8*)(Vt + (nd*16 + c)*32 + ((g ^ c3) * 8));
      o[nd] = mfma_bf16(ap, bv, o[nd]);
    }
    o[4] = mfma_bf16(ap, onesf.v, o[4]);   // ls accumulates in column 0
  }
#undef STAGE

  float rls[4];
  for (int r = 0; r < 4; ++r)
    rls[r] = 1.0f / __shfl(o[4][r], lane & 48);   // broadcast ls from c==0 lane of group
  for (int nd = 0; nd < 4; ++nd)
    for (int r = 0; r < 4; ++r)
      out[((size_t)b * SS + qrow[r]) * DD + hh*64 + nd*16 + c] = f2b(o[nd][r] * rls[r]);
}

// ---------------------------------------------------------------------------------------
extern "C" void kernel_launch(void* const* d_in, const int* in_sizes, int n_in,
                              void* d_out, int out_size, void* d_ws, size_t ws_size,
                              hipStream_t stream) {
  const float* x    = (const float*)d_in[0];
  const int*   npt  = (const int*)  d_in[1];
  const float* ln1g = (const float*)d_in[2];
  const float* ln1b = (const float*)d_in[3];
  const float* wqkv = (const float*)d_in[4];
  const float* bqkv = (const float*)d_in[5];
  const float* wo   = (const float*)d_in[6];
  const float* bo   = (const float*)d_in[7];
  const float* ln2g = (const float*)d_in[8];
  const float* ln2b = (const float*)d_in[9];
  const float* w1   = (const float*)d_in[10];
  const float* b1   = (const float*)d_in[11];
  const float* w2   = (const float*)d_in[12];
  const float* b2   = (const float*)d_in[13];
  const float* lnfg = (const float*)d_in[14];
  const float* lnfb = (const float*)d_in[15];

  char* ws = (char*)d_ws;
  size_t off = 0;
  u16*   wqkvT = (u16*)(ws + off);   off += (size_t)NL*TD*DD*2;
  u16*   woT   = (u16*)(ws + off);   off += (size_t)NL*DD*DD*2;
  u16*   w1T   = (u16*)(ws + off);   off += (size_t)NL*DFFN*DD*2;
  u16*   w2T   = (u16*)(ws + off);   off += (size_t)NL*DD*DFFN*2;
  float* h     = (float*)(ws + off); off += (size_t)MM*DD*4;
  u16*   lnb   = (u16*)(ws + off);   off += (size_t)MM*DD*2;
  u16*   Qb    = (u16*)(ws + off);   off += (size_t)BB*HH*SP*64*2;
  u16*   Kb    = (u16*)(ws + off);   off += (size_t)BB*HH*SP*64*2;
  u16*   VTb   = (u16*)(ws + off);   off += (size_t)BB*HH*64*SP*2;
  u16*   attnO = (u16*)(ws + off);   off += (size_t)MM*DD*2;
  u16*   ffh   = (u16*)(ws + off);   off += (size_t)MM*DFFN*2;

  const dim3 tb(32, 8);
  transpose_cast<<<dim3(TD/32,   DD/32,   NL), tb, 0, stream>>>(wqkv, wqkvT, DD,   TD);
  transpose_cast<<<dim3(DD/32,   DD/32,   NL), tb, 0, stream>>>(wo,   woT,   DD,   DD);
  transpose_cast<<<dim3(DFFN/32, DD/32,   NL), tb, 0, stream>>>(w1,   w1T,   DD,   DFFN);
  transpose_cast<<<dim3(DD/32,   DFFN/32, NL), tb, 0, stream>>>(w2,   w2T,   DFFN, DD);
  hipMemcpyAsync(h, x, (size_t)MM*DD*4, hipMemcpyDeviceToDevice, stream);
  hipMemsetAsync(Qb, 0, (size_t)3*BB*HH*SP*64*2, stream);   // zero Q/K/VT arena (pads)

  for (int l = 0; l < NL; ++l) {
    ln_kernel<0><<<MM, 256, 0, stream>>>(h, ln1g + (size_t)l*DD, ln1b + (size_t)l*DD, lnb, nullptr);
    gemm_bt<3><<<dim3(MM/128, TD/128), 256, 0, stream>>>(
        lnb, wqkvT + (size_t)l*TD*DD, bqkv + (size_t)l*TD, nullptr,
        Qb, Kb, VTb, TD, DD);
    attn_staged<<<dim3(BB*HH*8 + NTAIL), 512, 0, stream>>>(Qb, Kb, VTb, attnO, npt);
    gemm64<<<dim3(MM/64, DD/128), 256, 0, stream>>>(
        attnO, woT + (size_t)l*DD*DD, bo + (size_t)l*DD, h, h, DD, DD);
    ln_kernel<0><<<MM, 256, 0, stream>>>(h, ln2g + (size_t)l*DD, ln2b + (size_t)l*DD, lnb, nullptr);
    gemm_bt<1><<<dim3(MM/128, DFFN/128), 256, 0, stream>>>(
        lnb, w1T + (size_t)l*DFFN*DD, b1 + (size_t)l*DFFN, ffh,
        nullptr, nullptr, nullptr, DFFN, DD);
    gemm64<<<dim3(MM/64, DD/128), 256, 0, stream>>>(
        ffh, w2T + (size_t)l*DD*DFFN, b2 + (size_t)l*DD, h, h, DD, DFFN);
  }
  ln_kernel<1><<<MM, 256, 0, stream>>>(h, lnfg, lnfb, nullptr, (float*)d_out);
}

// Round 15
// 6112.448 us; speedup vs baseline: 1.1356x; 1.0072x over previous
//
#include <hip/hip_runtime.h>
#include <hip/hip_bf16.h>
#include <stdint.h>

#define DD   1024
#define TD   3072
#define DFFN 4096
#define NL   12
#define SS   1040
#define SP   1056          /* padded seq for attention operand arena */
#define BB   8
#define MM   (BB*SS)       /* 8320 */
#define HH   16
#define NTAIL 16           /* leading tail blocks in attn_staged grid */

typedef float  f32x4  __attribute__((ext_vector_type(4)));
typedef __bf16 bf16x8 __attribute__((ext_vector_type(8)));
typedef unsigned short u16;

union Bf8 { bf16x8 v; u16 s[8]; };

__device__ __forceinline__ u16 f2b(float f) {
  union { float f; unsigned u; } x; x.f = f;
  unsigned r = (x.u + 0x7FFFu + ((x.u >> 16) & 1u)) >> 16;
  return (u16)r;
}

__device__ __forceinline__ f32x4 mfma_bf16(bf16x8 a, bf16x8 b, f32x4 c) {
  return __builtin_amdgcn_mfma_f32_16x16x32_bf16(a, b, c, 0, 0, 0);
}

__device__ __forceinline__ void gload_lds16(const u16* g, u16* l) {
  __builtin_amdgcn_global_load_lds((const __attribute__((address_space(1))) void*)g,
                                   (__attribute__((address_space(3))) void*)l, 16, 0, 0);
}

// 16-lane max reduce via DPP (quad_perm xor1, xor2, row_ror:4, row_ror:8) — VALU-speed.
__device__ __forceinline__ float dppmax16(float t) {
  union { float f; int i; } u, v;
  u.f = t;
  v.i = __builtin_amdgcn_update_dpp(0, u.i, 0xB1, 0xF, 0xF, true);   // quad_perm [1,0,3,2]
  u.f = fmaxf(u.f, v.f);
  v.i = __builtin_amdgcn_update_dpp(0, u.i, 0x4E, 0xF, 0xF, true);   // quad_perm [2,3,0,1]
  u.f = fmaxf(u.f, v.f);
  v.i = __builtin_amdgcn_update_dpp(0, u.i, 0x124, 0xF, 0xF, true);  // row_ror:4
  u.f = fmaxf(u.f, v.f);
  v.i = __builtin_amdgcn_update_dpp(0, u.i, 0x128, 0xF, 0xF, true);  // row_ror:8
  u.f = fmaxf(u.f, v.f);
  return u.f;
}

// ---------------- weight cast+transpose: in (K,N) f32 -> out (N,K) bf16, per layer z ----
__global__ __launch_bounds__(256)
void transpose_cast(const float* __restrict__ in, u16* __restrict__ out, int K, int N) {
  __shared__ float tile[32][33];
  const int n0 = blockIdx.x * 32, k0 = blockIdx.y * 32;
  const size_t lb = (size_t)blockIdx.z * K * N;
  const int tx = threadIdx.x, ty = threadIdx.y;
  for (int j = 0; j < 4; ++j)
    tile[ty + 8*j][tx] = in[lb + (size_t)(k0 + ty + 8*j) * N + n0 + tx];
  __syncthreads();
  for (int j = 0; j < 4; ++j)
    out[lb + (size_t)(n0 + ty + 8*j) * K + k0 + tx] = f2b(tile[tx][ty + 8*j]);
}

// ---------------- LayerNorm: row of 1024, OUTF=0 -> bf16 out, OUTF=1 -> f32 out --------
template<int OUTF>
__global__ __launch_bounds__(256)
void ln_kernel(const float* __restrict__ in, const float* __restrict__ gam,
               const float* __restrict__ bet, u16* __restrict__ outb, float* __restrict__ outf) {
  const int row = blockIdx.x, t = threadIdx.x;
  const float4 v = ((const float4*)(in + (size_t)row * DD))[t];
  float s  = v.x + v.y + v.z + v.w;
  float s2 = v.x*v.x + v.y*v.y + v.z*v.z + v.w*v.w;
  for (int off = 1; off < 64; off <<= 1) { s += __shfl_xor(s, off); s2 += __shfl_xor(s2, off); }
  __shared__ float red[8];
  if ((t & 63) == 0) { red[t >> 6] = s; red[4 + (t >> 6)] = s2; }
  __syncthreads();
  s  = red[0] + red[1] + red[2] + red[3];
  s2 = red[4] + red[5] + red[6] + red[7];
  const float mu = s * (1.0f/1024.0f);
  const float var = s2 * (1.0f/1024.0f) - mu*mu;
  const float rs = rsqrtf(var + 1e-6f);
  const float4 gv = ((const float4*)gam)[t];
  const float4 bv = ((const float4*)bet)[t];
  const float y0 = (v.x - mu)*rs*gv.x + bv.x;
  const float y1 = (v.y - mu)*rs*gv.y + bv.y;
  const float y2 = (v.z - mu)*rs*gv.z + bv.z;
  const float y3 = (v.w - mu)*rs*gv.w + bv.w;
  if (OUTF) {
    float4 o; o.x=y0; o.y=y1; o.z=y2; o.w=y3;
    ((float4*)(outf + (size_t)row * DD))[t] = o;
  } else {
    ushort4 o; o.x=f2b(y0); o.y=f2b(y1); o.z=f2b(y2); o.w=f2b(y3);
    ((ushort4*)(outb + (size_t)row * DD))[t] = o;
  }
}

// ---------------- 128² GEMM: C(M,N) = A(M,K)bf16 @ Bt(N,K)bf16^T + bias [+ epi] --------
// EPI 1: gelu, write bf16.  EPI 2: +resid, write f32.  EPI 3: qkv scatter.
// nb-fastest decode: consecutive (same-XCD) blocks share the A-panel.
template<int EPI>
__global__ __launch_bounds__(256, 2)
void gemm_bt(const u16* __restrict__ A, const u16* __restrict__ Bt,
             const float* __restrict__ bias, const float* __restrict__ resid,
             float* outF, u16* outB,
             u16* __restrict__ qb, u16* __restrict__ kb, u16* __restrict__ vtb,
             int N, int K) {
  __shared__ u16 As[128*64];
  __shared__ u16 Bs[128*64];
  const int tid = threadIdx.x;

  const int nwg = gridDim.x * gridDim.y;
  int wgid = blockIdx.y * gridDim.x + blockIdx.x;
  wgid = (wgid & 7) * (nwg >> 3) + (wgid >> 3);
  const int nb = wgid % gridDim.y;
  const int mb = wgid / gridDim.y;
  const int m0 = mb * 128, n0 = nb * 128;

  const int lane = tid & 63, w = tid >> 6;
  const int wr = (w >> 1) * 64, wc = (w & 1) * 64;
  const int c = lane & 15, g = lane >> 4;

  f32x4 acc[4][4];
  for (int i = 0; i < 4; ++i) for (int j = 0; j < 4; ++j) acc[i][j] = f32x4{0.f,0.f,0.f,0.f};

  const int srow = tid >> 3, scg = tid & 7;
  const size_t aoff = (size_t)(m0 + srow) * K + scg * 8;
  const size_t boff = (size_t)(n0 + srow) * K + scg * 8;

  for (int kt = 0; kt < K; kt += 64) {
    for (int it = 0; it < 4; ++it) {
      gload_lds16(A  + aoff + (size_t)it * 32 * K + kt, As + (it*256 + tid) * 8);
      gload_lds16(Bt + boff + (size_t)it * 32 * K + kt, Bs + (it*256 + tid) * 8);
    }
    __syncthreads();
    for (int kk = 0; kk < 2; ++kk) {
      bf16x8 af[4], bfr[4];
      for (int i = 0; i < 4; ++i) af[i]  = *(const bf16x8*)(As + (wr + i*16 + c)*64 + kk*32 + g*8);
      for (int j = 0; j < 4; ++j) bfr[j] = *(const bf16x8*)(Bs + (wc + j*16 + c)*64 + kk*32 + g*8);
      for (int i = 0; i < 4; ++i)
        for (int j = 0; j < 4; ++j)
          acc[i][j] = mfma_bf16(af[i], bfr[j], acc[i][j]);
    }
    __syncthreads();
  }

  for (int j = 0; j < 4; ++j) {
    const int col = n0 + wc + j*16 + c;
    const float bcol = bias[col];
    for (int i = 0; i < 4; ++i) {
      const int row0 = m0 + wr + i*16 + 4*g;
      if (EPI == 3) {
        const int part = col >> 10;
        const int hh2  = (col >> 6) & 15;
        const int hd   = col & 63;
        const int bb   = (int)((unsigned)row0 / SS);
        const int s0   = row0 - bb * SS;          // 4-aligned; never crosses batch
        const size_t bh = (size_t)(bb * HH + hh2);
        if (part == 2) {
          ushort4 pk;
          pk.x = f2b(acc[i][j][0] + bcol);
          pk.y = f2b(acc[i][j][1] + bcol);
          pk.z = f2b(acc[i][j][2] + bcol);
          pk.w = f2b(acc[i][j][3] + bcol);
          *(ushort4*)(vtb + (bh*64 + hd)*SP + s0) = pk;
        } else if (part == 0) {
          for (int r = 0; r < 4; ++r)
            qb[(bh*SP + s0 + r)*64 + hd] = f2b((acc[i][j][r] + bcol) * 0.125f);
        } else {
          for (int r = 0; r < 4; ++r)
            kb[(bh*SP + s0 + r)*64 + hd] = f2b(acc[i][j][r] + bcol);
        }
      } else {
        for (int r = 0; r < 4; ++r) {
          const size_t idx = (size_t)(row0 + r) * N + col;
          const float v = acc[i][j][r] + bcol;
          if (EPI == 1) {
            const float z = 1.5957691216f * (v + 0.044715f * v * v * v);
            const float e = __expf(z);
            outB[idx] = f2b(v * e * __builtin_amdgcn_rcpf(e + 1.0f));
          } else {
            outF[idx] = v + resid[idx];
          }
        }
      }
    }
  }
}

// ---------------- 64x128-tile GEMM for WO (N=1024, K=1024): +resid, f32 out -----------
__global__ __launch_bounds__(256, 4)
void gemm64(const u16* __restrict__ A, const u16* __restrict__ Bt,
            const float* __restrict__ bias, const float* __restrict__ resid,
            float* __restrict__ outF, int N, int K) {
  __shared__ u16 As[64*64];
  __shared__ u16 Bs[128*64];
  const int tid = threadIdx.x;

  const int nwg = gridDim.x * gridDim.y;
  int wgid = blockIdx.y * gridDim.x + blockIdx.x;
  wgid = (wgid & 7) * (nwg >> 3) + (wgid >> 3);
  const int nb = wgid % gridDim.y;
  const int mb = wgid / gridDim.y;
  const int m0 = mb * 64, n0 = nb * 128;

  const int lane = tid & 63, w = tid >> 6;
  const int wr = (w >> 1) * 32, wc = (w & 1) * 64;
  const int c = lane & 15, g = lane >> 4;

  f32x4 acc[2][4];
  for (int i = 0; i < 2; ++i) for (int j = 0; j < 4; ++j) acc[i][j] = f32x4{0.f,0.f,0.f,0.f};

  const int srow = tid >> 3, scg = tid & 7;
  const size_t aoff = (size_t)(m0 + srow) * K + scg * 8;
  const size_t boff = (size_t)(n0 + srow) * K + scg * 8;

  for (int kt = 0; kt < K; kt += 64) {
    for (int it = 0; it < 2; ++it)
      gload_lds16(A  + aoff + (size_t)it * 32 * K + kt, As + (it*256 + tid) * 8);
    for (int it = 0; it < 4; ++it)
      gload_lds16(Bt + boff + (size_t)it * 32 * K + kt, Bs + (it*256 + tid) * 8);
    __syncthreads();
    for (int kk = 0; kk < 2; ++kk) {
      bf16x8 af[2], bfr[4];
      for (int i = 0; i < 2; ++i) af[i]  = *(const bf16x8*)(As + (wr + i*16 + c)*64 + kk*32 + g*8);
      for (int j = 0; j < 4; ++j) bfr[j] = *(const bf16x8*)(Bs + (wc + j*16 + c)*64 + kk*32 + g*8);
      for (int i = 0; i < 2; ++i)
        for (int j = 0; j < 4; ++j)
          acc[i][j] = mfma_bf16(af[i], bfr[j], acc[i][j]);
    }
    __syncthreads();
  }

  for (int j = 0; j < 4; ++j) {
    const int col = n0 + wc + j*16 + c;
    const float bcol = bias[col];
    for (int i = 0; i < 2; ++i) {
      const int row0 = m0 + wr + i*16 + 4*g;
      for (int r = 0; r < 4; ++r) {
        const size_t idx = (size_t)(row0 + r) * N + col;
        outF[idx] = acc[i][j][r] + bcol + resid[idx];
      }
    }
  }
}

// ---------------- staged attention + fused tail; 2 q-tiles per wave -------------------
// Blocks [0, NTAIL): tail path — wave w handles bh = blockIdx*8+w, q-tile 64, direct loads.
// Blocks [NTAIL, NTAIL+512): staged — sb = blockIdx-NTAIL, bh = sb & 127 (XCD-grouped:
//   4 blocks per bh, 128 apart -> same XCD), qg = sb>>7; wave w owns q-tiles
//   qg*16 + 2w + {0,1}. K-fragments loaded once per kt, shared by both q-tiles.
__global__ __launch_bounds__(512, 4)
void attn_staged(const u16* __restrict__ Qb, const u16* __restrict__ Kb,
                 const u16* __restrict__ VTb, u16* __restrict__ out,
                 const int* __restrict__ npt) {
  __shared__ u16 KV[2][4096];       // per buf: [0..2048) K tile, [2048..4096) V tile
  __shared__ u16 PT[8][640];        // per-wave P^T, 16 rows x 40 u16 (bf16)
  const int tid = threadIdx.x;
  const int w = tid >> 6, lane = tid & 63;
  const int c = lane & 15, g = lane >> 4;
  const int nin = npt[0];
  u16* pw = PT[w];

  if (blockIdx.x < NTAIL) {
    // ---------------- tail path: q-tile 64, direct global loads -----------------------
    const int bh = blockIdx.x * 8 + w;
    const int b = bh >> 4, hh = bh & 15;
    const int q0 = 64 * 16;

    bf16x8 aq0, aq1;
    {
      const u16* qp = Qb + ((size_t)bh * SP + q0 + c) * 64 + g * 8;
      aq0 = *(const bf16x8*)qp;
      aq1 = *(const bf16x8*)(qp + 32);
    }

    float m[4], ls[4];
    f32x4 o[4];
    int qrow[4];
    for (int r = 0; r < 4; ++r) { m[r] = -1e30f; ls[r] = 0.f; qrow[r] = q0 + 4*g + r; }
    for (int nd = 0; nd < 4; ++nd) o[nd] = f32x4{0.f,0.f,0.f,0.f};

    for (int kt = 0; kt < 33; ++kt) {
      const int k0 = kt * 32;

      f32x4 s[2];
      {
        const u16* kp0 = Kb + ((size_t)bh * SP + k0 + c) * 64 + g * 8;
        f32x4 z0 = f32x4{0.f,0.f,0.f,0.f};
        z0 = mfma_bf16(aq0, *(const bf16x8*)kp0, z0);
        z0 = mfma_bf16(aq1, *(const bf16x8*)(kp0 + 32), z0);
        s[0] = z0;
        const u16* kp1 = kp0 + 16 * 64;
        f32x4 z1 = f32x4{0.f,0.f,0.f,0.f};
        z1 = mfma_bf16(aq0, *(const bf16x8*)kp1, z1);
        z1 = mfma_bf16(aq1, *(const bf16x8*)(kp1 + 32), z1);
        s[1] = z1;
      }

      for (int jt = 0; jt < 2; ++jt) {
        const int j = k0 + jt*16 + c;
        for (int r = 0; r < 4; ++r) {
          const int q = qrow[r];
          const bool blocked = (j >= SS) || ((q >= nin) && (j >= nin) && (j > q));
          if (blocked) s[jt][r] = -1e30f;
        }
      }

      for (int r = 0; r < 4; ++r) {
        float t = fmaxf(s[0][r], s[1][r]);
        for (int off = 1; off < 16; off <<= 1) t = fmaxf(t, __shfl_xor(t, off));
        const float mn = fmaxf(m[r], t);
        const float al = __expf(m[r] - mn);
        m[r] = mn;
        const float p0 = __expf(s[0][r] - mn);
        const float p1 = __expf(s[1][r] - mn);
        s[0][r] = p0; s[1][r] = p1;
        float ps = p0 + p1;
        for (int off = 1; off < 16; off <<= 1) ps += __shfl_xor(ps, off);
        ls[r] = ls[r] * al + ps;
        for (int nd = 0; nd < 4; ++nd) o[nd][r] *= al;
      }

      for (int jt = 0; jt < 2; ++jt)
        for (int r = 0; r < 4; ++r)
          pw[(4*g + r)*40 + jt*16 + c] = f2b(s[jt][r]);
      __builtin_amdgcn_sched_barrier(0);
      bf16x8 ap = *(const bf16x8*)(pw + c*40 + 8*g);
      __builtin_amdgcn_sched_barrier(0);

      for (int nd = 0; nd < 4; ++nd) {
        const u16* vp = VTb + ((size_t)bh * 64 + nd*16 + c) * SP + k0 + 8*g;
        o[nd] = mfma_bf16(ap, *(const bf16x8*)vp, o[nd]);
      }
    }

    for (int nd = 0; nd < 4; ++nd)
      for (int r = 0; r < 4; ++r) {
        const float v = o[nd][r] / ls[r];
        out[((size_t)b * SS + qrow[r]) * DD + hh*64 + nd*16 + c] = f2b(v);
      }
    return;
  }

  // ---------------- staged path: 2 q-tiles per wave ----------------
  const int sb = blockIdx.x - NTAIL;      // [0, 512)
  const int bh = sb & 127;
  const int qg = sb >> 7;                 // 0..3
  const int b = bh >> 4, hh = bh & 15;

  const u16* ssrc; int kstr; u16* sdst;
  if (tid < 256) {
    const int row = tid >> 3, col8 = (tid & 7) ^ (row & 7);
    ssrc = Kb + ((size_t)bh * SP + row) * 64 + col8 * 8;
    kstr = 32 * 64;
    sdst = &KV[0][tid * 8];
  } else {
    const int t2 = tid - 256, row = t2 >> 2, col8 = (t2 & 3) ^ (row & 3);
    ssrc = VTb + ((size_t)bh * 64 + row) * SP + col8 * 8;
    kstr = 32;
    sdst = &KV[0][2048 + t2 * 8];
  }
#define STAGE(bufbit, kt) gload_lds16(ssrc + (size_t)(kt) * kstr, sdst + (bufbit) * 4096)

  bf16x8 aq[2][2];
  int q0[2];
#pragma unroll
  for (int qq = 0; qq < 2; ++qq) {
    q0[qq] = (qg * 16 + w * 2 + qq) * 16;
    const u16* qp = Qb + ((size_t)bh * SP + q0[qq] + c) * 64 + g * 8;
    aq[qq][0] = *(const bf16x8*)qp;
    aq[qq][1] = *(const bf16x8*)(qp + 32);
  }

  Bf8 onesf;
  for (int i = 0; i < 8; ++i) onesf.s[i] = (c == 0) ? (u16)0x3F80 : (u16)0;

  float m[2][4];
  f32x4 o[2][5];
#pragma unroll
  for (int qq = 0; qq < 2; ++qq) {
    for (int r = 0; r < 4; ++r) m[qq][r] = -1e30f;
    for (int nd = 0; nd < 5; ++nd) o[qq][nd] = f32x4{0.f,0.f,0.f,0.f};
  }
  const bool tregs0 = (q0[0] + 15) >= nin;
  const bool tregs1 = (q0[1] + 15) >= nin;
  const int c7 = c & 7, c3 = c & 3;

  STAGE(0, 0);

  for (int kt = 0; kt < 33; ++kt) {
    const int buf = kt & 1;
    __syncthreads();                   // buf staged (drains vmcnt) + prior-buf reads done
    if (kt < 32) STAGE(buf ^ 1, kt + 1);
    const u16* Kt = &KV[buf][0];
    const u16* Vt = &KV[buf][2048];
    const int k0 = kt * 32;

    // K fragments: loaded once, shared by both q-tiles
    bf16x8 k00 = *(const bf16x8*)(Kt + c*64        + ((g    ) ^ c7) * 8);
    bf16x8 k01 = *(const bf16x8*)(Kt + c*64        + ((g + 4) ^ c7) * 8);
    bf16x8 k10 = *(const bf16x8*)(Kt + (c+16)*64   + ((g    ) ^ c7) * 8);
    bf16x8 k11 = *(const bf16x8*)(Kt + (c+16)*64   + ((g + 4) ^ c7) * 8);

#pragma unroll
    for (int qq = 0; qq < 2; ++qq) {
      f32x4 s[2];
      {
        f32x4 z0 = f32x4{0.f,0.f,0.f,0.f};
        z0 = mfma_bf16(aq[qq][0], k00, z0);
        z0 = mfma_bf16(aq[qq][1], k01, z0);
        s[0] = z0;
        f32x4 z1 = f32x4{0.f,0.f,0.f,0.f};
        z1 = mfma_bf16(aq[qq][0], k10, z1);
        z1 = mfma_bf16(aq[qq][1], k11, z1);
        s[1] = z1;
      }

      const bool tregs = qq ? tregs1 : tregs0;
      if (tregs || (k0 + 31 >= SS)) {
        const int qr0 = q0[qq] + 4*g;
        for (int jt = 0; jt < 2; ++jt) {
          const int j = k0 + jt*16 + c;
          for (int r = 0; r < 4; ++r) {
            const int q = qr0 + r;
            const bool blocked = (j >= SS) || ((q >= nin) && (j >= nin) && (j > q));
            if (blocked) s[jt][r] = -1e30f;
          }
        }
      }

      for (int r = 0; r < 4; ++r) {
        const float t = dppmax16(fmaxf(s[0][r], s[1][r]));
        const float mn = fmaxf(m[qq][r], t);
        const float al = __expf(m[qq][r] - mn);
        m[qq][r] = mn;
        for (int nd = 0; nd < 5; ++nd) o[qq][nd][r] *= al;
        s[0][r] = __expf(s[0][r] - mn);
        s[1][r] = __expf(s[1][r] - mn);
      }

      // P^T via per-wave LDS (in-wave DS ordering; sched_barrier pins program order)
      for (int jt = 0; jt < 2; ++jt)
        for (int r = 0; r < 4; ++r)
          pw[(4*g + r)*40 + jt*16 + c] = f2b(s[jt][r]);
      __builtin_amdgcn_sched_barrier(0);
      bf16x8 ap = *(const bf16x8*)(pw + c*40 + 8*g);
      __builtin_amdgcn_sched_barrier(0);

      for (int nd = 0; nd < 4; ++nd) {
        bf16x8 bv = *(const bf16x8*)(Vt + (nd*16 + c)*32 + ((g ^ c3) * 8));
        o[qq][nd] = mfma_bf16(ap, bv, o[qq][nd]);
      }
      o[qq][4] = mfma_bf16(ap, onesf.v, o[qq][4]);   // ls accumulates in column 0
    }
  }
#undef STAGE

#pragma unroll
  for (int qq = 0; qq < 2; ++qq) {
    float rls[4];
    for (int r = 0; r < 4; ++r)
      rls[r] = 1.0f / __shfl(o[qq][4][r], lane & 48);
    const int qr0 = q0[qq] + 4*g;
    for (int nd = 0; nd < 4; ++nd)
      for (int r = 0; r < 4; ++r)
        out[((size_t)b * SS + qr0 + r) * DD + hh*64 + nd*16 + c] = f2b(o[qq][nd][r] * rls[r]);
  }
}

// ---------------------------------------------------------------------------------------
extern "C" void kernel_launch(void* const* d_in, const int* in_sizes, int n_in,
                              void* d_out, int out_size, void* d_ws, size_t ws_size,
                              hipStream_t stream) {
  const float* x    = (const float*)d_in[0];
  const int*   npt  = (const int*)  d_in[1];
  const float* ln1g = (const float*)d_in[2];
  const float* ln1b = (const float*)d_in[3];
  const float* wqkv = (const float*)d_in[4];
  const float* bqkv = (const float*)d_in[5];
  const float* wo   = (const float*)d_in[6];
  const float* bo   = (const float*)d_in[7];
  const float* ln2g = (const float*)d_in[8];
  const float* ln2b = (const float*)d_in[9];
  const float* w1   = (const float*)d_in[10];
  const float* b1   = (const float*)d_in[11];
  const float* w2   = (const float*)d_in[12];
  const float* b2   = (const float*)d_in[13];
  const float* lnfg = (const float*)d_in[14];
  const float* lnfb = (const float*)d_in[15];

  char* ws = (char*)d_ws;
  size_t off = 0;
  u16*   wqkvT = (u16*)(ws + off);   off += (size_t)NL*TD*DD*2;
  u16*   woT   = (u16*)(ws + off);   off += (size_t)NL*DD*DD*2;
  u16*   w1T   = (u16*)(ws + off);   off += (size_t)NL*DFFN*DD*2;
  u16*   w2T   = (u16*)(ws + off);   off += (size_t)NL*DD*DFFN*2;
  float* h     = (float*)(ws + off); off += (size_t)MM*DD*4;
  u16*   lnb   = (u16*)(ws + off);   off += (size_t)MM*DD*2;
  u16*   Qb    = (u16*)(ws + off);   off += (size_t)BB*HH*SP*64*2;
  u16*   Kb    = (u16*)(ws + off);   off += (size_t)BB*HH*SP*64*2;
  u16*   VTb   = (u16*)(ws + off);   off += (size_t)BB*HH*64*SP*2;
  u16*   attnO = (u16*)(ws + off);   off += (size_t)MM*DD*2;
  u16*   ffh   = (u16*)(ws + off);   off += (size_t)MM*DFFN*2;

  const dim3 tb(32, 8);
  transpose_cast<<<dim3(TD/32,   DD/32,   NL), tb, 0, stream>>>(wqkv, wqkvT, DD,   TD);
  transpose_cast<<<dim3(DD/32,   DD/32,   NL), tb, 0, stream>>>(wo,   woT,   DD,   DD);
  transpose_cast<<<dim3(DFFN/32, DD/32,   NL), tb, 0, stream>>>(w1,   w1T,   DD,   DFFN);
  transpose_cast<<<dim3(DD/32,   DFFN/32, NL), tb, 0, stream>>>(w2,   w2T,   DFFN, DD);
  hipMemcpyAsync(h, x, (size_t)MM*DD*4, hipMemcpyDeviceToDevice, stream);
  hipMemsetAsync(Qb, 0, (size_t)3*BB*HH*SP*64*2, stream);   // zero Q/K/VT arena (pads)

  for (int l = 0; l < NL; ++l) {
    ln_kernel<0><<<MM, 256, 0, stream>>>(h, ln1g + (size_t)l*DD, ln1b + (size_t)l*DD, lnb, nullptr);
    gemm_bt<3><<<dim3(MM/128, TD/128), 256, 0, stream>>>(
        lnb, wqkvT + (size_t)l*TD*DD, bqkv + (size_t)l*TD, nullptr, nullptr, nullptr,
        Qb, Kb, VTb, TD, DD);
    attn_staged<<<dim3(512 + NTAIL), 512, 0, stream>>>(Qb, Kb, VTb, attnO, npt);
    gemm64<<<dim3(MM/64, DD/128), 256, 0, stream>>>(
        attnO, woT + (size_t)l*DD*DD, bo + (size_t)l*DD, h, h, DD, DD);
    ln_kernel<0><<<MM, 256, 0, stream>>>(h, ln2g + (size_t)l*DD, ln2b + (size_t)l*DD, lnb, nullptr);
    gemm_bt<1><<<dim3(MM/128, DFFN/128), 256, 0, stream>>>(
        lnb, w1T + (size_t)l*DFFN*DD, b1 + (size_t)l*DFFN, nullptr, nullptr, ffh,
        nullptr, nullptr, nullptr, DFFN, DD);
    gemm_bt<2><<<dim3(MM/128, DD/128), 256, 0, stream>>>(
        ffh, w2T + (size_t)l*DD*DFFN, b2 + (size_t)l*DD, h, h, nullptr,
        nullptr, nullptr, nullptr, DD, DFFN);
  }
  ln_kernel<1><<<MM, 256, 0, stream>>>(h, lnfg, lnfb, nullptr, (float*)d_out);
}

// Round 16
// 5729.148 us; speedup vs baseline: 1.2116x; 1.0669x over previous
//
#include <hip/hip_runtime.h>
#include <hip/hip_bf16.h>
#include <stdint.h>

#define DD   1024
#define TD   3072
#define DFFN 4096
#define NL   12
#define SS   1040
#define SP   1056          /* padded seq for attention operand arena */
#define BB   8
#define MM   (BB*SS)       /* 8320 */
#define HH   16
#define NTAIL 32           /* leading tail blocks in attn_staged grid (4 waves each) */

typedef float  f32x4  __attribute__((ext_vector_type(4)));
typedef __bf16 bf16x8 __attribute__((ext_vector_type(8)));
typedef unsigned short u16;

union Bf8 { bf16x8 v; u16 s[8]; };

__device__ __forceinline__ u16 f2b(float f) {
  union { float f; unsigned u; } x; x.f = f;
  unsigned r = (x.u + 0x7FFFu + ((x.u >> 16) & 1u)) >> 16;
  return (u16)r;
}

__device__ __forceinline__ f32x4 mfma_bf16(bf16x8 a, bf16x8 b, f32x4 c) {
  return __builtin_amdgcn_mfma_f32_16x16x32_bf16(a, b, c, 0, 0, 0);
}

__device__ __forceinline__ void gload_lds16(const u16* g, u16* l) {
  __builtin_amdgcn_global_load_lds((const __attribute__((address_space(1))) void*)g,
                                   (__attribute__((address_space(3))) void*)l, 16, 0, 0);
}

// 16-lane max reduce via DPP (quad_perm xor1, xor2, row_ror:4, row_ror:8) — VALU-speed.
__device__ __forceinline__ float dppmax16(float t) {
  union { float f; int i; } u, v;
  u.f = t;
  v.i = __builtin_amdgcn_update_dpp(0, u.i, 0xB1, 0xF, 0xF, true);   // quad_perm [1,0,3,2]
  u.f = fmaxf(u.f, v.f);
  v.i = __builtin_amdgcn_update_dpp(0, u.i, 0x4E, 0xF, 0xF, true);   // quad_perm [2,3,0,1]
  u.f = fmaxf(u.f, v.f);
  v.i = __builtin_amdgcn_update_dpp(0, u.i, 0x124, 0xF, 0xF, true);  // row_ror:4
  u.f = fmaxf(u.f, v.f);
  v.i = __builtin_amdgcn_update_dpp(0, u.i, 0x128, 0xF, 0xF, true);  // row_ror:8
  u.f = fmaxf(u.f, v.f);
  return u.f;
}

// ---------------- weight cast+transpose: in (K,N) f32 -> out (N,K) bf16, per layer z ----
__global__ __launch_bounds__(256)
void transpose_cast(const float* __restrict__ in, u16* __restrict__ out, int K, int N) {
  __shared__ float tile[32][33];
  const int n0 = blockIdx.x * 32, k0 = blockIdx.y * 32;
  const size_t lb = (size_t)blockIdx.z * K * N;
  const int tx = threadIdx.x, ty = threadIdx.y;
  for (int j = 0; j < 4; ++j)
    tile[ty + 8*j][tx] = in[lb + (size_t)(k0 + ty + 8*j) * N + n0 + tx];
  __syncthreads();
  for (int j = 0; j < 4; ++j)
    out[lb + (size_t)(n0 + ty + 8*j) * K + k0 + tx] = f2b(tile[tx][ty + 8*j]);
}

// ---------------- LayerNorm: row of 1024, OUTF=0 -> bf16 out, OUTF=1 -> f32 out --------
template<int OUTF>
__global__ __launch_bounds__(256)
void ln_kernel(const float* __restrict__ in, const float* __restrict__ gam,
               const float* __restrict__ bet, u16* __restrict__ outb, float* __restrict__ outf) {
  const int row = blockIdx.x, t = threadIdx.x;
  const float4 v = ((const float4*)(in + (size_t)row * DD))[t];
  float s  = v.x + v.y + v.z + v.w;
  float s2 = v.x*v.x + v.y*v.y + v.z*v.z + v.w*v.w;
  for (int off = 1; off < 64; off <<= 1) { s += __shfl_xor(s, off); s2 += __shfl_xor(s2, off); }
  __shared__ float red[8];
  if ((t & 63) == 0) { red[t >> 6] = s; red[4 + (t >> 6)] = s2; }
  __syncthreads();
  s  = red[0] + red[1] + red[2] + red[3];
  s2 = red[4] + red[5] + red[6] + red[7];
  const float mu = s * (1.0f/1024.0f);
  const float var = s2 * (1.0f/1024.0f) - mu*mu;
  const float rs = rsqrtf(var + 1e-6f);
  const float4 gv = ((const float4*)gam)[t];
  const float4 bv = ((const float4*)bet)[t];
  const float y0 = (v.x - mu)*rs*gv.x + bv.x;
  const float y1 = (v.y - mu)*rs*gv.y + bv.y;
  const float y2 = (v.z - mu)*rs*gv.z + bv.z;
  const float y3 = (v.w - mu)*rs*gv.w + bv.w;
  if (OUTF) {
    float4 o; o.x=y0; o.y=y1; o.z=y2; o.w=y3;
    ((float4*)(outf + (size_t)row * DD))[t] = o;
  } else {
    ushort4 o; o.x=f2b(y0); o.y=f2b(y1); o.z=f2b(y2); o.w=f2b(y3);
    ((ushort4*)(outb + (size_t)row * DD))[t] = o;
  }
}

// ---------------- 128² GEMM: C(M,N) = A(M,K)bf16 @ Bt(N,K)bf16^T + bias [+ epi] --------
// EPI 1: gelu, write bf16.  EPI 2: +resid, write f32.  EPI 3: qkv scatter.
// nb-fastest decode: consecutive (same-XCD) blocks share the A-panel.
template<int EPI>
__global__ __launch_bounds__(256, 4)
void gemm_bt(const u16* __restrict__ A, const u16* __restrict__ Bt,
             const float* __restrict__ bias, const float* __restrict__ resid,
             float* outF, u16* outB,
             u16* __restrict__ qb, u16* __restrict__ kb, u16* __restrict__ vtb,
             int N, int K) {
  __shared__ u16 As[128*64];
  __shared__ u16 Bs[128*64];
  const int tid = threadIdx.x;

  const int nwg = gridDim.x * gridDim.y;
  int wgid = blockIdx.y * gridDim.x + blockIdx.x;
  wgid = (wgid & 7) * (nwg >> 3) + (wgid >> 3);
  const int nb = wgid % gridDim.y;
  const int mb = wgid / gridDim.y;
  const int m0 = mb * 128, n0 = nb * 128;

  const int lane = tid & 63, w = tid >> 6;
  const int wr = (w >> 1) * 64, wc = (w & 1) * 64;
  const int c = lane & 15, g = lane >> 4;

  f32x4 acc[4][4];
  for (int i = 0; i < 4; ++i) for (int j = 0; j < 4; ++j) acc[i][j] = f32x4{0.f,0.f,0.f,0.f};

  const int srow = tid >> 3, scg = tid & 7;
  const size_t aoff = (size_t)(m0 + srow) * K + scg * 8;
  const size_t boff = (size_t)(n0 + srow) * K + scg * 8;

  for (int kt = 0; kt < K; kt += 64) {
    for (int it = 0; it < 4; ++it) {
      gload_lds16(A  + aoff + (size_t)it * 32 * K + kt, As + (it*256 + tid) * 8);
      gload_lds16(Bt + boff + (size_t)it * 32 * K + kt, Bs + (it*256 + tid) * 8);
    }
    __syncthreads();
    for (int kk = 0; kk < 2; ++kk) {
      bf16x8 af[4], bfr[4];
      for (int i = 0; i < 4; ++i) af[i]  = *(const bf16x8*)(As + (wr + i*16 + c)*64 + kk*32 + g*8);
      for (int j = 0; j < 4; ++j) bfr[j] = *(const bf16x8*)(Bs + (wc + j*16 + c)*64 + kk*32 + g*8);
      for (int i = 0; i < 4; ++i)
        for (int j = 0; j < 4; ++j)
          acc[i][j] = mfma_bf16(af[i], bfr[j], acc[i][j]);
    }
    __syncthreads();
  }

  for (int j = 0; j < 4; ++j) {
    const int col = n0 + wc + j*16 + c;
    const float bcol = bias[col];
    for (int i = 0; i < 4; ++i) {
      const int row0 = m0 + wr + i*16 + 4*g;
      if (EPI == 3) {
        const int part = col >> 10;
        const int hh2  = (col >> 6) & 15;
        const int hd   = col & 63;
        const int bb   = (int)((unsigned)row0 / SS);
        const int s0   = row0 - bb * SS;          // 4-aligned; never crosses batch
        const size_t bh = (size_t)(bb * HH + hh2);
        if (part == 2) {
          ushort4 pk;
          pk.x = f2b(acc[i][j][0] + bcol);
          pk.y = f2b(acc[i][j][1] + bcol);
          pk.z = f2b(acc[i][j][2] + bcol);
          pk.w = f2b(acc[i][j][3] + bcol);
          *(ushort4*)(vtb + (bh*64 + hd)*SP + s0) = pk;
        } else if (part == 0) {
          for (int r = 0; r < 4; ++r)
            qb[(bh*SP + s0 + r)*64 + hd] = f2b((acc[i][j][r] + bcol) * 0.125f);
        } else {
          for (int r = 0; r < 4; ++r)
            kb[(bh*SP + s0 + r)*64 + hd] = f2b(acc[i][j][r] + bcol);
        }
      } else {
        for (int r = 0; r < 4; ++r) {
          const size_t idx = (size_t)(row0 + r) * N + col;
          const float v = acc[i][j][r] + bcol;
          if (EPI == 1) {
            const float z = 1.5957691216f * (v + 0.044715f * v * v * v);
            const float e = __expf(z);
            outB[idx] = f2b(v * e * __builtin_amdgcn_rcpf(e + 1.0f));
          } else {
            outF[idx] = v + resid[idx];
          }
        }
      }
    }
  }
}

// ---------------- 64x128-tile GEMM for WO (N=1024, K=1024): +resid, f32 out -----------
__global__ __launch_bounds__(256, 4)
void gemm64(const u16* __restrict__ A, const u16* __restrict__ Bt,
            const float* __restrict__ bias, const float* __restrict__ resid,
            float* __restrict__ outF, int N, int K) {
  __shared__ u16 As[64*64];
  __shared__ u16 Bs[128*64];
  const int tid = threadIdx.x;

  const int nwg = gridDim.x * gridDim.y;
  int wgid = blockIdx.y * gridDim.x + blockIdx.x;
  wgid = (wgid & 7) * (nwg >> 3) + (wgid >> 3);
  const int nb = wgid % gridDim.y;
  const int mb = wgid / gridDim.y;
  const int m0 = mb * 64, n0 = nb * 128;

  const int lane = tid & 63, w = tid >> 6;
  const int wr = (w >> 1) * 32, wc = (w & 1) * 64;
  const int c = lane & 15, g = lane >> 4;

  f32x4 acc[2][4];
  for (int i = 0; i < 2; ++i) for (int j = 0; j < 4; ++j) acc[i][j] = f32x4{0.f,0.f,0.f,0.f};

  const int srow = tid >> 3, scg = tid & 7;
  const size_t aoff = (size_t)(m0 + srow) * K + scg * 8;
  const size_t boff = (size_t)(n0 + srow) * K + scg * 8;

  for (int kt = 0; kt < K; kt += 64) {
    for (int it = 0; it < 2; ++it)
      gload_lds16(A  + aoff + (size_t)it * 32 * K + kt, As + (it*256 + tid) * 8);
    for (int it = 0; it < 4; ++it)
      gload_lds16(Bt + boff + (size_t)it * 32 * K + kt, Bs + (it*256 + tid) * 8);
    __syncthreads();
    for (int kk = 0; kk < 2; ++kk) {
      bf16x8 af[2], bfr[4];
      for (int i = 0; i < 2; ++i) af[i]  = *(const bf16x8*)(As + (wr + i*16 + c)*64 + kk*32 + g*8);
      for (int j = 0; j < 4; ++j) bfr[j] = *(const bf16x8*)(Bs + (wc + j*16 + c)*64 + kk*32 + g*8);
      for (int i = 0; i < 2; ++i)
        for (int j = 0; j < 4; ++j)
          acc[i][j] = mfma_bf16(af[i], bfr[j], acc[i][j]);
    }
    __syncthreads();
  }

  for (int j = 0; j < 4; ++j) {
    const int col = n0 + wc + j*16 + c;
    const float bcol = bias[col];
    for (int i = 0; i < 2; ++i) {
      const int row0 = m0 + wr + i*16 + 4*g;
      for (int r = 0; r < 4; ++r) {
        const size_t idx = (size_t)(row0 + r) * N + col;
        outF[idx] = acc[i][j][r] + bcol + resid[idx];
      }
    }
  }
}

// ---------------- staged attention + fused tail; 256-thr blocks, 2 q-tiles/wave -------
// Blocks [0, NTAIL=32): tail path — wave w (0..3) handles bh = blockIdx*4+w, q-tile 64.
// Blocks [NTAIL, NTAIL+1024): staged — sb = blockIdx-NTAIL, bh = sb & 127 (XCD-grouped:
//   8 blocks per bh, 128 apart -> same XCD), qg = sb>>7 (0..7); wave w owns q-tiles
//   qg*8 + w*2 + {0,1}. K-fragments loaded once per kt, shared by both q-tiles.
__global__ __launch_bounds__(256, 4)
void attn_staged(const u16* __restrict__ Qb, const u16* __restrict__ Kb,
                 const u16* __restrict__ VTb, u16* __restrict__ out,
                 const int* __restrict__ npt) {
  __shared__ u16 KV[2][4096];       // per buf: [0..2048) K tile, [2048..4096) V tile
  __shared__ u16 PT[4][640];        // per-wave P^T, 16 rows x 40 u16 (bf16)
  const int tid = threadIdx.x;
  const int w = tid >> 6, lane = tid & 63;
  const int c = lane & 15, g = lane >> 4;
  const int nin = npt[0];
  u16* pw = PT[w];

  if (blockIdx.x < NTAIL) {
    // ---------------- tail path: q-tile 64, direct global loads -----------------------
    const int bh = blockIdx.x * 4 + w;
    const int b = bh >> 4, hh = bh & 15;
    const int q0 = 64 * 16;

    bf16x8 aq0, aq1;
    {
      const u16* qp = Qb + ((size_t)bh * SP + q0 + c) * 64 + g * 8;
      aq0 = *(const bf16x8*)qp;
      aq1 = *(const bf16x8*)(qp + 32);
    }

    float m[4], ls[4];
    f32x4 o[4];
    int qrow[4];
    for (int r = 0; r < 4; ++r) { m[r] = -1e30f; ls[r] = 0.f; qrow[r] = q0 + 4*g + r; }
    for (int nd = 0; nd < 4; ++nd) o[nd] = f32x4{0.f,0.f,0.f,0.f};

    for (int kt = 0; kt < 33; ++kt) {
      const int k0 = kt * 32;

      f32x4 s[2];
      {
        const u16* kp0 = Kb + ((size_t)bh * SP + k0 + c) * 64 + g * 8;
        f32x4 z0 = f32x4{0.f,0.f,0.f,0.f};
        z0 = mfma_bf16(aq0, *(const bf16x8*)kp0, z0);
        z0 = mfma_bf16(aq1, *(const bf16x8*)(kp0 + 32), z0);
        s[0] = z0;
        const u16* kp1 = kp0 + 16 * 64;
        f32x4 z1 = f32x4{0.f,0.f,0.f,0.f};
        z1 = mfma_bf16(aq0, *(const bf16x8*)kp1, z1);
        z1 = mfma_bf16(aq1, *(const bf16x8*)(kp1 + 32), z1);
        s[1] = z1;
      }

      for (int jt = 0; jt < 2; ++jt) {
        const int j = k0 + jt*16 + c;
        for (int r = 0; r < 4; ++r) {
          const int q = qrow[r];
          const bool blocked = (j >= SS) || ((q >= nin) && (j >= nin) && (j > q));
          if (blocked) s[jt][r] = -1e30f;
        }
      }

      for (int r = 0; r < 4; ++r) {
        float t = fmaxf(s[0][r], s[1][r]);
        for (int off = 1; off < 16; off <<= 1) t = fmaxf(t, __shfl_xor(t, off));
        const float mn = fmaxf(m[r], t);
        const float al = __expf(m[r] - mn);
        m[r] = mn;
        const float p0 = __expf(s[0][r] - mn);
        const float p1 = __expf(s[1][r] - mn);
        s[0][r] = p0; s[1][r] = p1;
        float ps = p0 + p1;
        for (int off = 1; off < 16; off <<= 1) ps += __shfl_xor(ps, off);
        ls[r] = ls[r] * al + ps;
        for (int nd = 0; nd < 4; ++nd) o[nd][r] *= al;
      }

      for (int jt = 0; jt < 2; ++jt)
        for (int r = 0; r < 4; ++r)
          pw[(4*g + r)*40 + jt*16 + c] = f2b(s[jt][r]);
      __builtin_amdgcn_sched_barrier(0);
      bf16x8 ap = *(const bf16x8*)(pw + c*40 + 8*g);
      __builtin_amdgcn_sched_barrier(0);

      for (int nd = 0; nd < 4; ++nd) {
        const u16* vp = VTb + ((size_t)bh * 64 + nd*16 + c) * SP + k0 + 8*g;
        o[nd] = mfma_bf16(ap, *(const bf16x8*)vp, o[nd]);
      }
    }

    for (int nd = 0; nd < 4; ++nd)
      for (int r = 0; r < 4; ++r) {
        const float v = o[nd][r] / ls[r];
        out[((size_t)b * SS + qrow[r]) * DD + hh*64 + nd*16 + c] = f2b(v);
      }
    return;
  }

  // ---------------- staged path: 2 q-tiles per wave, 4 waves -----------------------
  const int sb = blockIdx.x - NTAIL;      // [0, 1024)
  const int bh = sb & 127;
  const int qg = sb >> 7;                 // 0..7
  const int b = bh >> 4, hh = bh & 15;

  // staging: 256 threads x 2 chunks of 16B. tid<128 -> K (chunks tid, tid+128);
  // tid>=128 -> V (chunks t2, t2+128).
  const u16 *ssrc0, *ssrc1; int kstr; u16 *sdst0, *sdst1;
  if (tid < 128) {
    const int i0 = tid, i1 = tid + 128;
    const int r0 = i0 >> 3, cg0 = (i0 & 7) ^ (r0 & 7);
    const int r1 = i1 >> 3, cg1 = (i1 & 7) ^ (r1 & 7);
    ssrc0 = Kb + ((size_t)bh * SP + r0) * 64 + cg0 * 8;
    ssrc1 = Kb + ((size_t)bh * SP + r1) * 64 + cg1 * 8;
    kstr = 32 * 64;
    sdst0 = &KV[0][i0 * 8];
    sdst1 = &KV[0][i1 * 8];
  } else {
    const int t2 = tid - 128;
    const int i0 = t2, i1 = t2 + 128;
    const int r0 = i0 >> 2, cg0 = (i0 & 3) ^ (r0 & 3);
    const int r1 = i1 >> 2, cg1 = (i1 & 3) ^ (r1 & 3);
    ssrc0 = VTb + ((size_t)bh * 64 + r0) * SP + cg0 * 8;
    ssrc1 = VTb + ((size_t)bh * 64 + r1) * SP + cg1 * 8;
    kstr = 32;
    sdst0 = &KV[0][2048 + i0 * 8];
    sdst1 = &KV[0][2048 + i1 * 8];
  }
#define STAGE(bufbit, kt) do { \
    gload_lds16(ssrc0 + (size_t)(kt) * kstr, sdst0 + (bufbit) * 4096); \
    gload_lds16(ssrc1 + (size_t)(kt) * kstr, sdst1 + (bufbit) * 4096); } while (0)

  bf16x8 aq[2][2];
  int q0[2];
#pragma unroll
  for (int qq = 0; qq < 2; ++qq) {
    q0[qq] = (qg * 8 + w * 2 + qq) * 16;
    const u16* qp = Qb + ((size_t)bh * SP + q0[qq] + c) * 64 + g * 8;
    aq[qq][0] = *(const bf16x8*)qp;
    aq[qq][1] = *(const bf16x8*)(qp + 32);
  }

  Bf8 onesf;
  for (int i = 0; i < 8; ++i) onesf.s[i] = (c == 0) ? (u16)0x3F80 : (u16)0;

  float m[2][4];
  f32x4 o[2][5];
#pragma unroll
  for (int qq = 0; qq < 2; ++qq) {
    for (int r = 0; r < 4; ++r) m[qq][r] = -1e30f;
    for (int nd = 0; nd < 5; ++nd) o[qq][nd] = f32x4{0.f,0.f,0.f,0.f};
  }
  const bool tregs0 = (q0[0] + 15) >= nin;
  const bool tregs1 = (q0[1] + 15) >= nin;
  const int c7 = c & 7, c3 = c & 3;

  STAGE(0, 0);

  for (int kt = 0; kt < 33; ++kt) {
    const int buf = kt & 1;
    __syncthreads();                   // buf staged (drains vmcnt) + prior-buf reads done
    if (kt < 32) STAGE(buf ^ 1, kt + 1);
    const u16* Kt = &KV[buf][0];
    const u16* Vt = &KV[buf][2048];
    const int k0 = kt * 32;

    // K fragments: loaded once, shared by both q-tiles
    bf16x8 k00 = *(const bf16x8*)(Kt + c*64        + ((g    ) ^ c7) * 8);
    bf16x8 k01 = *(const bf16x8*)(Kt + c*64        + ((g + 4) ^ c7) * 8);
    bf16x8 k10 = *(const bf16x8*)(Kt + (c+16)*64   + ((g    ) ^ c7) * 8);
    bf16x8 k11 = *(const bf16x8*)(Kt + (c+16)*64   + ((g + 4) ^ c7) * 8);

#pragma unroll
    for (int qq = 0; qq < 2; ++qq) {
      f32x4 s[2];
      {
        f32x4 z0 = f32x4{0.f,0.f,0.f,0.f};
        z0 = mfma_bf16(aq[qq][0], k00, z0);
        z0 = mfma_bf16(aq[qq][1], k01, z0);
        s[0] = z0;
        f32x4 z1 = f32x4{0.f,0.f,0.f,0.f};
        z1 = mfma_bf16(aq[qq][0], k10, z1);
        z1 = mfma_bf16(aq[qq][1], k11, z1);
        s[1] = z1;
      }

      const bool tregs = qq ? tregs1 : tregs0;
      if (tregs || (k0 + 31 >= SS)) {
        const int qr0 = q0[qq] + 4*g;
        for (int jt = 0; jt < 2; ++jt) {
          const int j = k0 + jt*16 + c;
          for (int r = 0; r < 4; ++r) {
            const int q = qr0 + r;
            const bool blocked = (j >= SS) || ((q >= nin) && (j >= nin) && (j > q));
            if (blocked) s[jt][r] = -1e30f;
          }
        }
      }

      for (int r = 0; r < 4; ++r) {
        const float t = dppmax16(fmaxf(s[0][r], s[1][r]));
        const float mn = fmaxf(m[qq][r], t);
        const float al = __expf(m[qq][r] - mn);
        m[qq][r] = mn;
        for (int nd = 0; nd < 5; ++nd) o[qq][nd][r] *= al;
        s[0][r] = __expf(s[0][r] - mn);
        s[1][r] = __expf(s[1][r] - mn);
      }

      // P^T via per-wave LDS (in-wave DS ordering; sched_barrier pins program order)
      for (int jt = 0; jt < 2; ++jt)
        for (int r = 0; r < 4; ++r)
          pw[(4*g + r)*40 + jt*16 + c] = f2b(s[jt][r]);
      __builtin_amdgcn_sched_barrier(0);
      bf16x8 ap = *(const bf16x8*)(pw + c*40 + 8*g);
      __builtin_amdgcn_sched_barrier(0);

      for (int nd = 0; nd < 4; ++nd) {
        bf16x8 bv = *(const bf16x8*)(Vt + (nd*16 + c)*32 + ((g ^ c3) * 8));
        o[qq][nd] = mfma_bf16(ap, bv, o[qq][nd]);
      }
      o[qq][4] = mfma_bf16(ap, onesf.v, o[qq][4]);   // ls accumulates in column 0
    }
  }
#undef STAGE

#pragma unroll
  for (int qq = 0; qq < 2; ++qq) {
    float rls[4];
    for (int r = 0; r < 4; ++r)
      rls[r] = 1.0f / __shfl(o[qq][4][r], lane & 48);
    const int qr0 = q0[qq] + 4*g;
    for (int nd = 0; nd < 4; ++nd)
      for (int r = 0; r < 4; ++r)
        out[((size_t)b * SS + qr0 + r) * DD + hh*64 + nd*16 + c] = f2b(o[qq][nd][r] * rls[r]);
  }
}

// ---------------------------------------------------------------------------------------
extern "C" void kernel_launch(void* const* d_in, const int* in_sizes, int n_in,
                              void* d_out, int out_size, void* d_ws, size_t ws_size,
                              hipStream_t stream) {
  const float* x    = (const float*)d_in[0];
  const int*   npt  = (const int*)  d_in[1];
  const float* ln1g = (const float*)d_in[2];
  const float* ln1b = (const float*)d_in[3];
  const float* wqkv = (const float*)d_in[4];
  const float* bqkv = (const float*)d_in[5];
  const float* wo   = (const float*)d_in[6];
  const float* bo   = (const float*)d_in[7];
  const float* ln2g = (const float*)d_in[8];
  const float* ln2b = (const float*)d_in[9];
  const float* w1   = (const float*)d_in[10];
  const float* b1   = (const float*)d_in[11];
  const float* w2   = (const float*)d_in[12];
  const float* b2   = (const float*)d_in[13];
  const float* lnfg = (const float*)d_in[14];
  const float* lnfb = (const float*)d_in[15];

  char* ws = (char*)d_ws;
  size_t off = 0;
  u16*   wqkvT = (u16*)(ws + off);   off += (size_t)NL*TD*DD*2;
  u16*   woT   = (u16*)(ws + off);   off += (size_t)NL*DD*DD*2;
  u16*   w1T   = (u16*)(ws + off);   off += (size_t)NL*DFFN*DD*2;
  u16*   w2T   = (u16*)(ws + off);   off += (size_t)NL*DD*DFFN*2;
  float* h     = (float*)(ws + off); off += (size_t)MM*DD*4;
  u16*   lnb   = (u16*)(ws + off);   off += (size_t)MM*DD*2;
  u16*   Qb    = (u16*)(ws + off);   off += (size_t)BB*HH*SP*64*2;
  u16*   Kb    = (u16*)(ws + off);   off += (size_t)BB*HH*SP*64*2;
  u16*   VTb   = (u16*)(ws + off);   off += (size_t)BB*HH*64*SP*2;
  u16*   attnO = (u16*)(ws + off);   off += (size_t)MM*DD*2;
  u16*   ffh   = (u16*)(ws + off);   off += (size_t)MM*DFFN*2;

  const dim3 tb(32, 8);
  transpose_cast<<<dim3(TD/32,   DD/32,   NL), tb, 0, stream>>>(wqkv, wqkvT, DD,   TD);
  transpose_cast<<<dim3(DD/32,   DD/32,   NL), tb, 0, stream>>>(wo,   woT,   DD,   DD);
  transpose_cast<<<dim3(DFFN/32, DD/32,   NL), tb, 0, stream>>>(w1,   w1T,   DD,   DFFN);
  transpose_cast<<<dim3(DD/32,   DFFN/32, NL), tb, 0, stream>>>(w2,   w2T,   DFFN, DD);
  hipMemcpyAsync(h, x, (size_t)MM*DD*4, hipMemcpyDeviceToDevice, stream);
  hipMemsetAsync(Qb, 0, (size_t)3*BB*HH*SP*64*2, stream);   // zero Q/K/VT arena (pads)

  for (int l = 0; l < NL; ++l) {
    ln_kernel<0><<<MM, 256, 0, stream>>>(h, ln1g + (size_t)l*DD, ln1b + (size_t)l*DD, lnb, nullptr);
    gemm_bt<3><<<dim3(MM/128, TD/128), 256, 0, stream>>>(
        lnb, wqkvT + (size_t)l*TD*DD, bqkv + (size_t)l*TD, nullptr, nullptr, nullptr,
        Qb, Kb, VTb, TD, DD);
    attn_staged<<<dim3(1024 + NTAIL), 256, 0, stream>>>(Qb, Kb, VTb, attnO, npt);
    gemm64<<<dim3(MM/64, DD/128), 256, 0, stream>>>(
        attnO, woT + (size_t)l*DD*DD, bo + (size_t)l*DD, h, h, DD, DD);
    ln_kernel<0><<<MM, 256, 0, stream>>>(h, ln2g + (size_t)l*DD, ln2b + (size_t)l*DD, lnb, nullptr);
    gemm_bt<1><<<dim3(MM/128, DFFN/128), 256, 0, stream>>>(
        lnb, w1T + (size_t)l*DFFN*DD, b1 + (size_t)l*DFFN, nullptr, nullptr, ffh,
        nullptr, nullptr, nullptr, DFFN, DD);
    gemm_bt<2><<<dim3(MM/128, DD/128), 256, 0, stream>>>(
        ffh, w2T + (size_t)l*DD*DFFN, b2 + (size_t)l*DD, h, h, nullptr,
        nullptr, nullptr, nullptr, DD, DFFN);
  }
  ln_kernel<1><<<MM, 256, 0, stream>>>(h, lnfg, lnfb, nullptr, (float*)d_out);
}